// Round 2
// baseline (2481.163 us; speedup 1.0000x reference)
//
#include <hip/hip_runtime.h>
#include <math.h>

#pragma clang fp contract(off)

#define QN   512   // queries per image
#define NN   768   // total targets (bs*T)
#define BSZ  32    // batch
#define TPI  24    // targets per image
#define NCLS 92    // classes

// ---------- XLA-faithful special functions ----------

// XLA ElementalIrEmitter::EmitErfF32: Eigen rational approx, Horner via FMA.
__device__ __forceinline__ float xla_erf_f32(float x) {
#pragma clang fp contract(off)
  float x2 = x * x;
  float p = -2.72614225801306e-10f;
  p = fmaf(x2, p, 2.77068142495902e-08f);
  p = fmaf(x2, p, -2.10102402082508e-06f);
  p = fmaf(x2, p, -5.69250639462346e-05f);
  p = fmaf(x2, p, -7.34990630326855e-04f);
  p = fmaf(x2, p, -2.95459980854025e-03f);
  p = fmaf(x2, p, -1.60960333262415e-02f);
  p = x * p;
  float q = -1.45660718464996e-05f;
  q = fmaf(x2, q, -2.13374055278905e-04f);
  q = fmaf(x2, q, -1.68282697438203e-03f);
  q = fmaf(x2, q, -7.37332916720468e-03f);
  q = fmaf(x2, q, -1.42647390514189e-02f);
  float r = p / q;
  if (fabsf(x) >= 3.832506856900711f) r = copysignf(1.0f, x);
  return r;
}

// CHLO erf_inv f32 decomposition (Giles): w = -log1p(-x*x), two branches,
// plain mul/add (no FMA).  log1p large-|x| path per XLA EmitLog1p:
// log(1+x), computed correctly-rounded via double log.
__device__ __forceinline__ float xla_erfinv_f32(float b) {
#pragma clang fp contract(off)
  float bb = b * b;
  float u = (-bb) + 1.0f;              // FAdd(x, 1) with x = -b*b
  float w = -((float)log((double)u));  // Neg(Log(u)), correctly rounded
  float p;
  if (w < 5.0f) {
    float ww = w - 2.5f;
    p = 2.81022636e-08f;
    p = p * ww + 3.43273939e-07f;
    p = p * ww - 3.5233877e-06f;
    p = p * ww - 4.39150654e-06f;
    p = p * ww + 0.00021858087f;
    p = p * ww - 0.00125372503f;
    p = p * ww - 0.00417768164f;
    p = p * ww + 0.246640727f;
    p = p * ww + 1.50140941f;
  } else {
    float ww = (float)sqrt((double)w) - 3.0f;
    p = -0.000200214257f;
    p = p * ww + 0.000100950558f;
    p = p * ww + 0.00134934322f;
    p = p * ww - 0.00367342844f;
    p = p * ww + 0.00573950773f;
    p = p * ww - 0.0076224613f;
    p = p * ww + 0.00943887047f;
    p = p * ww + 1.00167406f;
    p = p * ww + 2.83297682f;
  }
  return p * b;
}

// ---------- Stage 1: softmax stats (sequential f32, XLA reduce order) ----------

__global__ void k_softmax_stats(const float* __restrict__ logits,
                                float* __restrict__ mx, float* __restrict__ sm) {
#pragma clang fp contract(off)
  int r = blockIdx.x * blockDim.x + threadIdx.x;
  if (r >= BSZ * QN) return;
  const float* row = logits + (size_t)r * NCLS;
  float m = -INFINITY;
  for (int j = 0; j < NCLS; ++j) m = fmaxf(m, row[j]);
  float s = 0.0f;
  for (int j = 0; j < NCLS; ++j) s += expf(row[j] - m);
  mx[r] = m;
  sm[r] = s;
}

// ---------- Stage 2: build B (column-major [N][Q]), B[n*512+q] = fx_T[q,n] ----------

__global__ void k_build(const float* __restrict__ logits,
                        const float* __restrict__ pboxes,
                        const float* __restrict__ tboxes,
                        const int* __restrict__ tlabels,
                        const float* __restrict__ mx,
                        const float* __restrict__ sm,
                        float* __restrict__ B) {
#pragma clang fp contract(off)
  int t = blockIdx.x * blockDim.x + threadIdx.x;
  if (t >= QN * NN) return;
  int n = t >> 9;            // target (column)
  int q = t & (QN - 1);      // query (row)
  int b = n / TPI;           // batch of this target (block-diag select)
  int r = b * QN + q;        // flattened prediction row

  // cost_class = -softmax(logits)[r, label_n]
  int lab = tlabels[n];
  float pc = expf(logits[(size_t)r * NCLS + lab] - mx[r]) / sm[r];
  float cost_class = -pc;

  float4 pb = ((const float4*)pboxes)[r];
  float4 tb = ((const float4*)tboxes)[n];

  // L1 cdist, sequential reduce order over 4
  float cost_bbox = ((fabsf(pb.x - tb.x) + fabsf(pb.y - tb.y)) +
                     fabsf(pb.z - tb.z)) + fabsf(pb.w - tb.w);

  // cxcywh -> xyxy (contraction OFF so 0.5*w stays a separate mul)
  float p0 = pb.x - 0.5f * pb.z;
  float p1 = pb.y - 0.5f * pb.w;
  float p2 = pb.x + 0.5f * pb.z;
  float p3 = pb.y + 0.5f * pb.w;
  float t0 = tb.x - 0.5f * tb.z;
  float t1 = tb.y - 0.5f * tb.w;
  float t2 = tb.x + 0.5f * tb.z;
  float t3 = tb.y + 0.5f * tb.w;

  float area1 = (p2 - p0) * (p3 - p1);
  float area2 = (t2 - t0) * (t3 - t1);
  float ltx = fmaxf(p0, t0), lty = fmaxf(p1, t1);
  float rbx = fminf(p2, t2), rby = fminf(p3, t3);
  float whx = fmaxf(rbx - ltx, 0.0f), why = fmaxf(rby - lty, 0.0f);
  float inter = whx * why;
  float uni = (area1 + area2) - inter;
  float iou = inter / uni;
  float l2x = fminf(p0, t0), l2y = fminf(p1, t1);
  float r2x = fmaxf(p2, t2), r2y = fmaxf(p3, t3);
  float w2x = fmaxf(r2x - l2x, 0.0f), w2y = fmaxf(r2y - l2y, 0.0f);
  float area = w2x * w2y;
  float giou = iou - (area - uni) / area;

  float C = (cost_bbox + cost_class) + (-giou);

  // prob = Normal(-5.5, 2.5).cdf(-C); fx = HalfNormal(0.3).icdf(prob)
  float z = (-C + 5.5f) / 3.5355339059327378f;     // (-C - mu) / (sigma*sqrt2)
  float prob = 0.5f * (1.0f + xla_erf_f32(z));
  float fx = 0.4242640687119285f * xla_erfinv_f32(prob);  // 0.3*sqrt(2)*erfinv

  B[t] = fx;
}

// ---------- Stage 3: initial per-column top-2 gap ----------

__global__ void k_top2_init(const float* __restrict__ B, float* __restrict__ ad) {
  int n = blockIdx.x * 4 + (threadIdx.x >> 6);   // one wave per column
  int lane = threadIdx.x & 63;
  const float* cp = B + (size_t)n * QN;
  float v1 = -INFINITY, v2 = -INFINITY;
#pragma unroll
  for (int k = 0; k < QN / 64; ++k) {
    float v = fminf(cp[lane + 64 * k], 100.0f);
    if (v > v1) { v2 = v1; v1 = v; }
    else if (v > v2) v2 = v;
  }
  for (int off = 32; off > 0; off >>= 1) {
    float o1 = __shfl_xor(v1, off);
    float o2 = __shfl_xor(v2, off);
    if (o1 > v1) { v2 = fmaxf(v1, o2); v1 = o1; }
    else v2 = fmaxf(v2, o1);
  }
  if (lane == 0) ad[n] = v1 - v2;   // == |second - best|
}

// ---------- Stage 4: the 768-iteration sequential assignment scan ----------

__global__ void __launch_bounds__(256) k_scan(float* B, const float* __restrict__ ad_init) {
  __shared__ float ad[NN];
  __shared__ float wv[4];
  __shared__ int   wi[4];
  __shared__ int   s_col, s_row;
  const int t = threadIdx.x;
  const int lane = t & 63;
  const int wave = t >> 6;

  for (int i = t; i < NN; i += 256) ad[i] = ad_init[i];
  __syncthreads();

  for (int it = 0; it < NN; ++it) {
    // Phase A: col = argmax_n ad[n]  (first index on ties, like jnp.argmax)
    float bv = -INFINITY; int bi = NN;
    for (int i = t; i < NN; i += 256) {
      float v = ad[i];
      if (v > bv || (v == bv && i < bi)) { bv = v; bi = i; }
    }
    for (int off = 32; off > 0; off >>= 1) {
      float ov = __shfl_xor(bv, off);
      int   oi = __shfl_xor(bi, off);
      if (ov > bv || (ov == bv && oi < bi)) { bv = ov; bi = oi; }
    }
    if (lane == 0) { wv[wave] = bv; wi[wave] = bi; }
    __syncthreads();
    if (t == 0) {
      float fv = wv[0]; int fi = wi[0];
      for (int k = 1; k < 4; ++k)
        if (wv[k] > fv || (wv[k] == fv && wi[k] < fi)) { fv = wv[k]; fi = wi[k]; }
      s_col = fi;
    }
    __syncthreads();
    const int col = s_col;

    // Phase B: row = argmax_q B[q, col]  (raw values, first index on ties)
    const float* colp = B + (size_t)col * QN;
    {
      float v0 = colp[t], v1 = colp[t + 256];
      bv = v0; bi = t;
      if (v1 > bv) { bv = v1; bi = t + 256; }
    }
    for (int off = 32; off > 0; off >>= 1) {
      float ov = __shfl_xor(bv, off);
      int   oi = __shfl_xor(bi, off);
      if (ov > bv || (ov == bv && oi < bi)) { bv = ov; bi = oi; }
    }
    if (lane == 0) { wv[wave] = bv; wi[wave] = bi; }
    __syncthreads();
    if (t == 0) {
      float fv = wv[0]; int fi = wi[0];
      for (int k = 1; k < 4; ++k)
        if (wv[k] > fv || (wv[k] == fv && wi[k] < fi)) { fv = wv[k]; fi = wi[k]; }
      s_row = fi;
    }
    __syncthreads();
    const int row = s_row;

    // Phase C: B[:,col]=0 ; then B[row,0]=0, B[row,1]=0 (row_lookups-values-
    // as-indices bug, faithfully) ; then B[row,col]=-1e-7
    B[(size_t)col * QN + t] = 0.0f;
    B[(size_t)col * QN + t + 256] = 0.0f;
    __syncthreads();
    if (t == 0) {
      B[row] = 0.0f;                        // B[row, 0]
      B[QN + row] = 0.0f;                   // B[row, 1]
      B[(size_t)col * QN + row] = -1e-07f;  // B[row, col]
    }
    __syncthreads();

    // Phase D: refresh gaps.  Zeroed column's top2 is (0,0) exactly (511
    // zeros + one -1e-7) -> ad[col]=0.  Columns 0 and 1 need a rescan.
    if (wave == 0) {
      if (lane == 0) ad[col] = 0.0f;
    } else if (wave <= 2) {
      int cc = wave - 1;
      const float* cp = B + (size_t)cc * QN;
      float v1 = -INFINITY, v2 = -INFINITY;
#pragma unroll
      for (int k = 0; k < QN / 64; ++k) {
        float v = fminf(cp[lane + 64 * k], 100.0f);
        if (v > v1) { v2 = v1; v1 = v; }
        else if (v > v2) v2 = v;
      }
      for (int off = 32; off > 0; off >>= 1) {
        float o1 = __shfl_xor(v1, off);
        float o2 = __shfl_xor(v2, off);
        if (o1 > v1) { v2 = fmaxf(v1, o2); v1 = o1; }
        else v2 = fmaxf(v2, o1);
      }
      if (lane == 0) ad[cc] = v1 - v2;
    }
    __syncthreads();
  }
}

// ---------- Stage 5: emit boolean as INT32 0/1, row-major [Q][N] ----------

__global__ void k_out(const float* __restrict__ B, int* __restrict__ out, int total) {
  int t = blockIdx.x * blockDim.x + threadIdx.x;
  if (t >= total) return;
  int q = t / NN;
  int n = t - q * NN;
  out[t] = (B[(size_t)n * QN + q] < 0.0f) ? 1 : 0;
}

extern "C" void kernel_launch(void* const* d_in, const int* in_sizes, int n_in,
                              void* d_out, int out_size, void* d_ws, size_t ws_size,
                              hipStream_t stream) {
  const float* logits  = (const float*)d_in[0];  // [32,512,92]
  const float* pboxes  = (const float*)d_in[1];  // [32,512,4]
  const float* tboxes  = (const float*)d_in[2];  // [768,4]
  const int*   tlabels = (const int*)d_in[3];    // [768]

  float* B  = (float*)d_ws;            // 393216 f32, column-major [N][Q]
  float* mx = B + QN * NN;             // 16384
  float* sm = mx + BSZ * QN;           // 16384
  float* ad = sm + BSZ * QN;           // 768
  int* out = (int*)d_out;

  hipLaunchKernelGGL(k_softmax_stats, dim3((BSZ * QN) / 256), dim3(256), 0, stream,
                     logits, mx, sm);
  hipLaunchKernelGGL(k_build, dim3((QN * NN) / 256), dim3(256), 0, stream,
                     logits, pboxes, tboxes, tlabels, mx, sm, B);
  hipLaunchKernelGGL(k_top2_init, dim3(NN / 4), dim3(256), 0, stream, B, ad);
  hipLaunchKernelGGL(k_scan, dim3(1), dim3(256), 0, stream, B, ad);
  hipLaunchKernelGGL(k_out, dim3((QN * NN) / 256), dim3(256), 0, stream,
                     B, out, QN * NN);
}

// Round 3
// 1575.728 us; speedup vs baseline: 1.5746x; 1.5746x over previous
//
#include <hip/hip_runtime.h>
#include <math.h>

#pragma clang fp contract(off)

#define QN   512   // queries per image
#define NN   768   // total targets (bs*T)
#define BSZ  32    // batch
#define TPI  24    // targets per image
#define NCLS 92    // classes

// ---------- XLA-faithful special functions (verified bit-exact, round 2) ----------

__device__ __forceinline__ float xla_erf_f32(float x) {
#pragma clang fp contract(off)
  float x2 = x * x;
  float p = -2.72614225801306e-10f;
  p = fmaf(x2, p, 2.77068142495902e-08f);
  p = fmaf(x2, p, -2.10102402082508e-06f);
  p = fmaf(x2, p, -5.69250639462346e-05f);
  p = fmaf(x2, p, -7.34990630326855e-04f);
  p = fmaf(x2, p, -2.95459980854025e-03f);
  p = fmaf(x2, p, -1.60960333262415e-02f);
  p = x * p;
  float q = -1.45660718464996e-05f;
  q = fmaf(x2, q, -2.13374055278905e-04f);
  q = fmaf(x2, q, -1.68282697438203e-03f);
  q = fmaf(x2, q, -7.37332916720468e-03f);
  q = fmaf(x2, q, -1.42647390514189e-02f);
  float r = p / q;
  if (fabsf(x) >= 3.832506856900711f) r = copysignf(1.0f, x);
  return r;
}

__device__ __forceinline__ float xla_erfinv_f32(float b) {
#pragma clang fp contract(off)
  float bb = b * b;
  float u = (-bb) + 1.0f;
  float w = -((float)log((double)u));
  float p;
  if (w < 5.0f) {
    float ww = w - 2.5f;
    p = 2.81022636e-08f;
    p = p * ww + 3.43273939e-07f;
    p = p * ww - 3.5233877e-06f;
    p = p * ww - 4.39150654e-06f;
    p = p * ww + 0.00021858087f;
    p = p * ww - 0.00125372503f;
    p = p * ww - 0.00417768164f;
    p = p * ww + 0.246640727f;
    p = p * ww + 1.50140941f;
  } else {
    float ww = (float)sqrt((double)w) - 3.0f;
    p = -0.000200214257f;
    p = p * ww + 0.000100950558f;
    p = p * ww + 0.00134934322f;
    p = p * ww - 0.00367342844f;
    p = p * ww + 0.00573950773f;
    p = p * ww - 0.0076224613f;
    p = p * ww + 0.00943887047f;
    p = p * ww + 1.00167406f;
    p = p * ww + 2.83297682f;
  }
  return p * b;
}

// ---------- Stage 1: softmax stats ----------

__global__ void k_softmax_stats(const float* __restrict__ logits,
                                float* __restrict__ mx, float* __restrict__ sm) {
#pragma clang fp contract(off)
  int r = blockIdx.x * blockDim.x + threadIdx.x;
  if (r >= BSZ * QN) return;
  const float* row = logits + (size_t)r * NCLS;
  float m = -INFINITY;
  for (int j = 0; j < NCLS; ++j) m = fmaxf(m, row[j]);
  float s = 0.0f;
  for (int j = 0; j < NCLS; ++j) s += expf(row[j] - m);
  mx[r] = m;
  sm[r] = s;
}

// ---------- Stage 2: build B column-major [N][Q] ----------

__global__ void k_build(const float* __restrict__ logits,
                        const float* __restrict__ pboxes,
                        const float* __restrict__ tboxes,
                        const int* __restrict__ tlabels,
                        const float* __restrict__ mx,
                        const float* __restrict__ sm,
                        float* __restrict__ B) {
#pragma clang fp contract(off)
  int t = blockIdx.x * blockDim.x + threadIdx.x;
  if (t >= QN * NN) return;
  int n = t >> 9;
  int q = t & (QN - 1);
  int b = n / TPI;
  int r = b * QN + q;

  int lab = tlabels[n];
  float pc = expf(logits[(size_t)r * NCLS + lab] - mx[r]) / sm[r];
  float cost_class = -pc;

  float4 pb = ((const float4*)pboxes)[r];
  float4 tb = ((const float4*)tboxes)[n];

  float cost_bbox = ((fabsf(pb.x - tb.x) + fabsf(pb.y - tb.y)) +
                     fabsf(pb.z - tb.z)) + fabsf(pb.w - tb.w);

  float p0 = pb.x - 0.5f * pb.z;
  float p1 = pb.y - 0.5f * pb.w;
  float p2 = pb.x + 0.5f * pb.z;
  float p3 = pb.y + 0.5f * pb.w;
  float t0 = tb.x - 0.5f * tb.z;
  float t1 = tb.y - 0.5f * tb.w;
  float t2 = tb.x + 0.5f * tb.z;
  float t3 = tb.y + 0.5f * tb.w;

  float area1 = (p2 - p0) * (p3 - p1);
  float area2 = (t2 - t0) * (t3 - t1);
  float ltx = fmaxf(p0, t0), lty = fmaxf(p1, t1);
  float rbx = fminf(p2, t2), rby = fminf(p3, t3);
  float whx = fmaxf(rbx - ltx, 0.0f), why = fmaxf(rby - lty, 0.0f);
  float inter = whx * why;
  float uni = (area1 + area2) - inter;
  float iou = inter / uni;
  float l2x = fminf(p0, t0), l2y = fminf(p1, t1);
  float r2x = fmaxf(p2, t2), r2y = fmaxf(p3, t3);
  float w2x = fmaxf(r2x - l2x, 0.0f), w2y = fmaxf(r2y - l2y, 0.0f);
  float area = w2x * w2y;
  float giou = iou - (area - uni) / area;

  float C = (cost_bbox + cost_class) + (-giou);

  float z = (-C + 5.5f) / 3.5355339059327378f;
  float prob = 0.5f * (1.0f + xla_erf_f32(z));
  float fx = 0.4242640687119285f * xla_erfinv_f32(prob);

  B[t] = fx;
}

// ---------- Stage 3: per-column init: gap (clamped top2) + raw argmax ----------

__global__ void k_init(const float* __restrict__ B, float* __restrict__ ad,
                       int* __restrict__ am) {
  int n = blockIdx.x * 4 + (threadIdx.x >> 6);   // one wave per column
  int lane = threadIdx.x & 63;
  const float* cp = B + (size_t)n * QN;
  float v1 = -INFINITY, v2 = -INFINITY, bv = -INFINITY;
  int bi = QN;
#pragma unroll
  for (int k = 0; k < QN / 64; ++k) {
    float raw = cp[lane + 64 * k];
    float v = fminf(raw, 100.0f);
    if (v > v1) { v2 = v1; v1 = v; }
    else if (v > v2) v2 = v;
    if (raw > bv) { bv = raw; bi = lane + 64 * k; }   // in-lane ascending idx: > keeps first
  }
  for (int off = 32; off > 0; off >>= 1) {
    float o1 = __shfl_xor(v1, off), o2 = __shfl_xor(v2, off);
    float ov = __shfl_xor(bv, off); int oi = __shfl_xor(bi, off);
    if (o1 > v1) { v2 = fmaxf(v1, o2); v1 = o1; }
    else v2 = fmaxf(v2, o1);
    if (ov > bv || (ov == bv && oi < bi)) { bv = ov; bi = oi; }
  }
  if (lane == 0) { ad[n] = v1 - v2; am[n] = bi; }
}

// ---------- Stage 4: single-wave LDS-resident assignment scan ----------
// Invariant: only columns {0, 1, already-picked} are ever modified by the
// reference. Unpicked col>=2 keeps initial values -> row is the precomputed
// am[col]; picked col>=2 is {0s, -1e-7 at r} -> row=(r==0)?1:0. Columns 0/1
// live as exact LDS mirrors. Global traffic per iteration: zero.

__global__ void __launch_bounds__(64) k_scan(const float* __restrict__ B,
                                             const float* __restrict__ ad_g,
                                             const int* __restrict__ am_g,
                                             int* __restrict__ asg_out) {
  __shared__ float ad[NN];     // gap cache (cols 0,1 entries unused)
  __shared__ float m0[QN];     // exact mirror of B[:,0]
  __shared__ float m1[QN];     // exact mirror of B[:,1]
  __shared__ int   am[NN];     // initial raw argmax per column
  __shared__ int   asg[NN];    // current assigned row per column, -1 = none
  const int lane = threadIdx.x;

#pragma unroll
  for (int k = 0; k < NN / 64; ++k) {
    int i = lane + 64 * k;
    ad[i] = ad_g[i];
    am[i] = am_g[i];
    asg[i] = -1;
  }
#pragma unroll
  for (int k = 0; k < QN / 64; ++k) {
    m0[lane + 64 * k] = B[lane + 64 * k];
    m1[lane + 64 * k] = B[QN + lane + 64 * k];
  }
  __syncthreads();

  for (int it = 0; it < NN; ++it) {
    // --- fused reduce: top2(clamp m0) || top2(clamp m1) || argmax ad[2..] ---
    float a1 = -INFINITY, a2 = -INFINITY;
    float b1 = -INFINITY, b2 = -INFINITY;
    float cv = -INFINITY; int ci = NN;
#pragma unroll
    for (int k = 0; k < QN / 64; ++k) {
      float x = fminf(m0[lane + 64 * k], 100.0f);
      if (x > a1) { a2 = a1; a1 = x; } else if (x > a2) a2 = x;
      float y = fminf(m1[lane + 64 * k], 100.0f);
      if (y > b1) { b2 = b1; b1 = y; } else if (y > b2) b2 = y;
    }
#pragma unroll
    for (int k = 0; k < NN / 64; ++k) {
      int i = lane + 64 * k;
      float v = ad[i];
      if (i >= 2 && v > cv) { cv = v; ci = i; }
    }
    for (int off = 32; off > 0; off >>= 1) {
      float oa1 = __shfl_xor(a1, off), oa2 = __shfl_xor(a2, off);
      float ob1 = __shfl_xor(b1, off), ob2 = __shfl_xor(b2, off);
      float ocv = __shfl_xor(cv, off); int oci = __shfl_xor(ci, off);
      if (oa1 > a1) { a2 = fmaxf(a1, oa2); a1 = oa1; } else a2 = fmaxf(a2, oa1);
      if (ob1 > b1) { b2 = fmaxf(b1, ob2); b1 = ob1; } else b2 = fmaxf(b2, ob1);
      if (ocv > cv || (ocv == cv && oci < ci)) { cv = ocv; ci = oci; }
    }
    float gap0 = a1 - a2, gap1 = b1 - b2;
    int col = 0; float best = gap0;
    if (gap1 > best) { best = gap1; col = 1; }   // strict >: idx 0 wins ties
    if (cv > best)  { best = cv;  col = ci; }    // strict >: smaller idx wins

    // --- Phase B: row = argmax of current column ---
    int row;
    if (col >= 2) {
      int r = asg[col];                       // LDS broadcast (uniform addr)
      row = (r >= 0) ? ((r == 0) ? 1 : 0) : am[col];
    } else {
      float bv = -INFINITY; int bi = QN;
#pragma unroll
      for (int k = 0; k < QN / 64; ++k) {
        float v = (col == 0) ? m0[lane + 64 * k] : m1[lane + 64 * k];
        if (v > bv) { bv = v; bi = lane + 64 * k; }
      }
      for (int off = 32; off > 0; off >>= 1) {
        float ov = __shfl_xor(bv, off); int oi = __shfl_xor(bi, off);
        if (ov > bv || (ov == bv && oi < bi)) { bv = ov; bi = oi; }
      }
      row = bi;
    }

    // --- Phase C: replicate reference write sequence exactly ---
    if (col == 0) {
#pragma unroll
      for (int k = 0; k < QN / 64; ++k) m0[lane + 64 * k] = 0.0f;
    } else if (col == 1) {
#pragma unroll
      for (int k = 0; k < QN / 64; ++k) m1[lane + 64 * k] = 0.0f;
    }
    __syncthreads();
    if (lane == 0) {
      asg[col] = -1;                       // B[:,col] = 0 erases col's -1e-7
      m0[row] = 0.0f;                      // B[row, 0] = 0
      m1[row] = 0.0f;                      // B[row, 1] = 0
      if (asg[0] == row) asg[0] = -1;      // erased a prior assignment in col 0
      if (asg[1] == row) asg[1] = -1;      // ... in col 1
      if (col == 0) m0[row] = -1e-07f;     // B[row, col] = -1e-7
      else if (col == 1) m1[row] = -1e-07f;
      asg[col] = row;
      ad[col] = 0.0f;                      // processed column: top2=(0,0)
    }
    __syncthreads();
  }

#pragma unroll
  for (int k = 0; k < NN / 64; ++k) {
    int i = lane + 64 * k;
    asg_out[i] = asg[i];
  }
}

// ---------- Stage 5: emit boolean as INT32 0/1, row-major [Q][N] ----------

__global__ void k_out(const int* __restrict__ asg, int* __restrict__ out, int total) {
  int t = blockIdx.x * blockDim.x + threadIdx.x;
  if (t >= total) return;
  int q = t / NN;
  int n = t - q * NN;
  out[t] = (asg[n] == q) ? 1 : 0;
}

extern "C" void kernel_launch(void* const* d_in, const int* in_sizes, int n_in,
                              void* d_out, int out_size, void* d_ws, size_t ws_size,
                              hipStream_t stream) {
  const float* logits  = (const float*)d_in[0];  // [32,512,92]
  const float* pboxes  = (const float*)d_in[1];  // [32,512,4]
  const float* tboxes  = (const float*)d_in[2];  // [768,4]
  const int*   tlabels = (const int*)d_in[3];    // [768]

  float* B    = (float*)d_ws;            // 393216 f32, column-major [N][Q]
  float* mx   = B + QN * NN;             // 16384
  float* sm   = mx + BSZ * QN;           // 16384
  float* ad   = sm + BSZ * QN;           // 768
  int*   am   = (int*)(ad + NN);         // 768
  int*   asgg = am + NN;                 // 768
  int*   out  = (int*)d_out;

  hipLaunchKernelGGL(k_softmax_stats, dim3((BSZ * QN) / 256), dim3(256), 0, stream,
                     logits, mx, sm);
  hipLaunchKernelGGL(k_build, dim3((QN * NN) / 256), dim3(256), 0, stream,
                     logits, pboxes, tboxes, tlabels, mx, sm, B);
  hipLaunchKernelGGL(k_init, dim3(NN / 4), dim3(256), 0, stream, B, ad, am);
  hipLaunchKernelGGL(k_scan, dim3(1), dim3(64), 0, stream, B, ad, am, asgg);
  hipLaunchKernelGGL(k_out, dim3((QN * NN) / 256), dim3(256), 0, stream,
                     asgg, out, QN * NN);
}

// Round 4
// 667.934 us; speedup vs baseline: 3.7147x; 2.3591x over previous
//
#include <hip/hip_runtime.h>
#include <math.h>

#pragma clang fp contract(off)

#define QN   512   // queries per image
#define NN   768   // total targets (bs*T)
#define BSZ  32    // batch
#define TPI  24    // targets per image
#define NCLS 92    // classes

// ---------- XLA-faithful special functions (verified bit-exact, round 2) ----------

__device__ __forceinline__ float xla_erf_f32(float x) {
#pragma clang fp contract(off)
  float x2 = x * x;
  float p = -2.72614225801306e-10f;
  p = fmaf(x2, p, 2.77068142495902e-08f);
  p = fmaf(x2, p, -2.10102402082508e-06f);
  p = fmaf(x2, p, -5.69250639462346e-05f);
  p = fmaf(x2, p, -7.34990630326855e-04f);
  p = fmaf(x2, p, -2.95459980854025e-03f);
  p = fmaf(x2, p, -1.60960333262415e-02f);
  p = x * p;
  float q = -1.45660718464996e-05f;
  q = fmaf(x2, q, -2.13374055278905e-04f);
  q = fmaf(x2, q, -1.68282697438203e-03f);
  q = fmaf(x2, q, -7.37332916720468e-03f);
  q = fmaf(x2, q, -1.42647390514189e-02f);
  float r = p / q;
  if (fabsf(x) >= 3.832506856900711f) r = copysignf(1.0f, x);
  return r;
}

__device__ __forceinline__ float xla_erfinv_f32(float b) {
#pragma clang fp contract(off)
  float bb = b * b;
  float u = (-bb) + 1.0f;
  float w = -((float)log((double)u));
  float p;
  if (w < 5.0f) {
    float ww = w - 2.5f;
    p = 2.81022636e-08f;
    p = p * ww + 3.43273939e-07f;
    p = p * ww - 3.5233877e-06f;
    p = p * ww - 4.39150654e-06f;
    p = p * ww + 0.00021858087f;
    p = p * ww - 0.00125372503f;
    p = p * ww - 0.00417768164f;
    p = p * ww + 0.246640727f;
    p = p * ww + 1.50140941f;
  } else {
    float ww = (float)sqrt((double)w) - 3.0f;
    p = -0.000200214257f;
    p = p * ww + 0.000100950558f;
    p = p * ww + 0.00134934322f;
    p = p * ww - 0.00367342844f;
    p = p * ww + 0.00573950773f;
    p = p * ww - 0.0076224613f;
    p = p * ww + 0.00943887047f;
    p = p * ww + 1.00167406f;
    p = p * ww + 2.83297682f;
  }
  return p * b;
}

// ---------- Stage 1: softmax stats ----------

__global__ void k_softmax_stats(const float* __restrict__ logits,
                                float* __restrict__ mx, float* __restrict__ sm) {
#pragma clang fp contract(off)
  int r = blockIdx.x * blockDim.x + threadIdx.x;
  if (r >= BSZ * QN) return;
  const float* row = logits + (size_t)r * NCLS;
  float m = -INFINITY;
  for (int j = 0; j < NCLS; ++j) m = fmaxf(m, row[j]);
  float s = 0.0f;
  for (int j = 0; j < NCLS; ++j) s += expf(row[j] - m);
  mx[r] = m;
  sm[r] = s;
}

// ---------- Stage 2: build B column-major [N][Q] ----------

__global__ void k_build(const float* __restrict__ logits,
                        const float* __restrict__ pboxes,
                        const float* __restrict__ tboxes,
                        const int* __restrict__ tlabels,
                        const float* __restrict__ mx,
                        const float* __restrict__ sm,
                        float* __restrict__ B) {
#pragma clang fp contract(off)
  int t = blockIdx.x * blockDim.x + threadIdx.x;
  if (t >= QN * NN) return;
  int n = t >> 9;
  int q = t & (QN - 1);
  int b = n / TPI;
  int r = b * QN + q;

  int lab = tlabels[n];
  float pc = expf(logits[(size_t)r * NCLS + lab] - mx[r]) / sm[r];
  float cost_class = -pc;

  float4 pb = ((const float4*)pboxes)[r];
  float4 tb = ((const float4*)tboxes)[n];

  float cost_bbox = ((fabsf(pb.x - tb.x) + fabsf(pb.y - tb.y)) +
                     fabsf(pb.z - tb.z)) + fabsf(pb.w - tb.w);

  float p0 = pb.x - 0.5f * pb.z;
  float p1 = pb.y - 0.5f * pb.w;
  float p2 = pb.x + 0.5f * pb.z;
  float p3 = pb.y + 0.5f * pb.w;
  float t0 = tb.x - 0.5f * tb.z;
  float t1 = tb.y - 0.5f * tb.w;
  float t2 = tb.x + 0.5f * tb.z;
  float t3 = tb.y + 0.5f * tb.w;

  float area1 = (p2 - p0) * (p3 - p1);
  float area2 = (t2 - t0) * (t3 - t1);
  float ltx = fmaxf(p0, t0), lty = fmaxf(p1, t1);
  float rbx = fminf(p2, t2), rby = fminf(p3, t3);
  float whx = fmaxf(rbx - ltx, 0.0f), why = fmaxf(rby - lty, 0.0f);
  float inter = whx * why;
  float uni = (area1 + area2) - inter;
  float iou = inter / uni;
  float l2x = fminf(p0, t0), l2y = fminf(p1, t1);
  float r2x = fmaxf(p2, t2), r2y = fmaxf(p3, t3);
  float w2x = fmaxf(r2x - l2x, 0.0f), w2y = fmaxf(r2y - l2y, 0.0f);
  float area = w2x * w2y;
  float giou = iou - (area - uni) / area;

  float C = (cost_bbox + cost_class) + (-giou);

  float z = (-C + 5.5f) / 3.5355339059327378f;
  float prob = 0.5f * (1.0f + xla_erf_f32(z));
  float fx = 0.4242640687119285f * xla_erfinv_f32(prob);

  B[t] = fx;
}

// ---------- Stage 3: per-column init: gap (clamped top2) + raw argmax ----------

__global__ void k_init(const float* __restrict__ B, float* __restrict__ ad,
                       int* __restrict__ am) {
  int n = blockIdx.x * 4 + (threadIdx.x >> 6);   // one wave per column
  int lane = threadIdx.x & 63;
  const float* cp = B + (size_t)n * QN;
  float v1 = -INFINITY, v2 = -INFINITY, bv = -INFINITY;
  int bi = QN;
#pragma unroll
  for (int k = 0; k < QN / 64; ++k) {
    float raw = cp[lane + 64 * k];
    float v = fminf(raw, 100.0f);
    if (v > v1) { v2 = v1; v1 = v; }
    else if (v > v2) v2 = v;
    if (raw > bv) { bv = raw; bi = lane + 64 * k; }
  }
  for (int off = 32; off > 0; off >>= 1) {
    float o1 = __shfl_xor(v1, off), o2 = __shfl_xor(v2, off);
    float ov = __shfl_xor(bv, off); int oi = __shfl_xor(bi, off);
    if (o1 > v1) { v2 = fmaxf(v1, o2); v1 = o1; }
    else v2 = fmaxf(v2, o1);
    if (ov > bv || (ov == bv && oi < bi)) { bv = ov; bi = oi; }
  }
  if (lane == 0) { ad[n] = v1 - v2; am[n] = bi; }
}

// ---------- Stage 4 helpers ----------

// (max, count) over clamped arr values strictly below `bound`
__device__ __forceinline__ void wave_maxcount(const float* arr, int lane, float bound,
                                              float& mx, int& cnt) {
  float m = -INFINITY; int c = 0;
#pragma unroll
  for (int k = 0; k < QN / 64; ++k) {
    float v = fminf(arr[lane + 64 * k], 100.0f);
    if (v < bound) {
      if (v > m) { m = v; c = 1; }
      else if (v == m) c++;
    }
  }
  for (int off = 32; off > 0; off >>= 1) {
    float om = __shfl_xor(m, off);
    int oc = __shfl_xor(c, off);
    if (om > m) { m = om; c = oc; }
    else if (om == m) c += oc;
  }
  mx = m; cnt = c;
}

// raw argmax, first index on ties
__device__ __forceinline__ int wave_argmax(const float* arr, int lane) {
  float bv = -INFINITY; int bi = 0x7fffffff;
#pragma unroll
  for (int k = 0; k < QN / 64; ++k) {
    float v = arr[lane + 64 * k];
    if (v > bv) { bv = v; bi = lane + 64 * k; }
  }
  for (int off = 32; off > 0; off >>= 1) {
    float ov = __shfl_xor(bv, off);
    int oi = __shfl_xor(bi, off);
    if (ov > bv || (ov == bv && oi < bi)) { bv = ov; bi = oi; }
  }
  return bi;
}

// Multiset top-2 (a1 x c1, then a2 = max distinct below a1, x c2).
// Apply "remove x, insert 0". Returns true if a full rescan is required
// (physical LDS array must already contain the inserted 0).
__device__ __forceinline__ bool ms_update(float x, float& a1, int& c1, float& a2, int& c2) {
  x = fminf(x, 100.0f);
  bool rescan = false;
  if (x == a1) {
    if (--c1 == 0) rescan = true;
  } else if (x == a2) {
    if (--c2 == 0) rescan = true;
  }
  if (!rescan) {
    if (0.0f > a1) { a2 = a1; c2 = c1; a1 = 0.0f; c1 = 1; }
    else if (0.0f == a1) c1++;
    else if (0.0f > a2) { a2 = 0.0f; c2 = 1; }
    else if (0.0f == a2) c2++;
  }
  return rescan;
}

// ---------- Stage 4: single-wave scan with presorted static gaps ----------
// Cols >=2: ad static until picked; picked cols (ad=0) can never win again
// (selection requires strictly beating gap0 >= 0, col 0 wins ties). So the
// c>=2 pick order = descending sort of initial ad, popped monotonically.
// gap0/gap1 maintained as exact clamped top-2 multisets of the m0/m1 mirrors.

__global__ void __launch_bounds__(64) k_scan(const float* __restrict__ B,
                                             const float* __restrict__ ad_g,
                                             const int* __restrict__ am_g,
                                             int* __restrict__ asg_out) {
  __shared__ unsigned long long skey[1024];
  __shared__ float m0[QN];
  __shared__ float m1[QN];
  __shared__ int asg[NN];
  const int lane = threadIdx.x;

  // mirrors + asg init + key build
#pragma unroll
  for (int k = 0; k < QN / 64; ++k) {
    m0[lane + 64 * k] = B[lane + 64 * k];
    m1[lane + 64 * k] = B[QN + lane + 64 * k];
  }
#pragma unroll
  for (int k = 0; k < NN / 64; ++k) {
    int n = lane + 64 * k;
    asg[n] = -1;
    unsigned long long key = 0ull;
    if (n >= 2) {
      unsigned vb = __float_as_uint(ad_g[n]);      // ad >= 0: bits monotone
      unsigned lo = ((unsigned)(1023 - n) << 16) | (unsigned)am_g[n];
      key = ((unsigned long long)vb << 32) | (unsigned long long)lo;
    }
    skey[n] = key;
  }
#pragma unroll
  for (int k = NN / 64; k < 1024 / 64; ++k) skey[lane + 64 * k] = 0ull;
  __syncthreads();

  // bitonic sort, descending
  for (int k = 2; k <= 1024; k <<= 1) {
    for (int j = k >> 1; j > 0; j >>= 1) {
      for (int t = lane; t < 1024; t += 64) {
        int l = t ^ j;
        if (l > t) {
          unsigned long long a = skey[t], b = skey[l];
          bool sw = ((t & k) == 0) ? (a < b) : (a > b);
          if (sw) { skey[t] = b; skey[l] = a; }
        }
      }
      __syncthreads();
    }
  }

  // initial top-2 multiset state for cols 0 and 1
  float a1, a2, b1, b2; int c1, c2, d1, d2;
  wave_maxcount(m0, lane, INFINITY, a1, c1);
  wave_maxcount(m0, lane, a1, a2, c2);
  wave_maxcount(m1, lane, INFINITY, b1, d1);
  wave_maxcount(m1, lane, b1, b2, d2);

  int p = 0;
  unsigned long long k0 = skey[0], k1 = skey[1];
  int negpos0 = -1, negpos1 = -1;     // position of -1e-7 in trivial m0/m1
  bool trivial0 = false, trivial1 = false;
  int asg0 = -1, asg1 = -1;

  for (int it = 0; it < NN; ++it) {
    // --- selection: first-index argmax over [gap0, gap1, ad[2..]] ---
    float gap0 = (c1 >= 2) ? 0.0f : (a1 - a2);
    float gap1 = (d1 >= 2) ? 0.0f : (b1 - b2);
    int col = 0; float best = gap0;
    if (gap1 > best) { best = gap1; col = 1; }
    float cv = __uint_as_float((unsigned)(k0 >> 32));
    int krow = 0;
    if (cv > best) {
      unsigned lo = (unsigned)k0;
      col = 1023 - (int)(lo >> 16);
      krow = (int)(lo & 0xFFFF);
      k0 = k1;
      ++p;
      k1 = skey[p + 1];               // prefetch, off critical path
    }

    if (col >= 2) {
      // first (and only) pick of this column: row = precomputed argmax
      int row = krow;
      float x0 = m0[row];
      float x1 = m1[row];
      if (lane == 0) {
        m0[row] = 0.0f;               // B[row,0] = 0
        m1[row] = 0.0f;               // B[row,1] = 0
        asg[col] = row;               // B[row,col] = -1e-7 (permanent)
      }
      if (negpos0 == row) negpos0 = -1;
      if (negpos1 == row) negpos1 = -1;
      if (ms_update(x0, a1, c1, a2, c2)) {
        __syncthreads();
        wave_maxcount(m0, lane, INFINITY, a1, c1);
        wave_maxcount(m0, lane, a1, a2, c2);
      }
      if (ms_update(x1, b1, d1, b2, d2)) {
        __syncthreads();
        wave_maxcount(m1, lane, INFINITY, b1, d1);
        wave_maxcount(m1, lane, b1, b2, d2);
      }
      if (asg0 == row) asg0 = -1;
      if (asg1 == row) asg1 = -1;
    } else if (col == 0) {
      int row;
      if (trivial0) row = (negpos0 == 0) ? 1 : 0;   // {0s, -1e-7@negpos0}
      else row = wave_argmax(m0, lane);
      float x1 = m1[row];
#pragma unroll
      for (int k = 0; k < QN / 64; ++k) m0[lane + 64 * k] = 0.0f;
      if (lane == 0) {
        m0[row] = -1e-07f;            // net effect of the write sequence
        m1[row] = 0.0f;
      }
      __syncthreads();
      a1 = 0.0f; c1 = QN - 1; a2 = -1e-07f; c2 = 1;
      trivial0 = true; negpos0 = row;
      if (negpos1 == row) negpos1 = -1;
      if (ms_update(x1, b1, d1, b2, d2)) {
        __syncthreads();
        wave_maxcount(m1, lane, INFINITY, b1, d1);
        wave_maxcount(m1, lane, b1, b2, d2);
      }
      asg0 = row;
      if (asg1 == row) asg1 = -1;
    } else { // col == 1
      int row;
      if (trivial1) row = (negpos1 == 0) ? 1 : 0;
      else row = wave_argmax(m1, lane);
      float x0 = m0[row];
#pragma unroll
      for (int k = 0; k < QN / 64; ++k) m1[lane + 64 * k] = 0.0f;
      if (lane == 0) {
        m1[row] = -1e-07f;
        m0[row] = 0.0f;
      }
      __syncthreads();
      b1 = 0.0f; d1 = QN - 1; b2 = -1e-07f; d2 = 1;
      trivial1 = true; negpos1 = row;
      if (negpos0 == row) negpos0 = -1;
      if (ms_update(x0, a1, c1, a2, c2)) {
        __syncthreads();
        wave_maxcount(m0, lane, INFINITY, a1, c1);
        wave_maxcount(m0, lane, a1, a2, c2);
      }
      asg1 = row;
      if (asg0 == row) asg0 = -1;
    }
  }

  if (lane == 0) { asg[0] = asg0; asg[1] = asg1; }
  __syncthreads();
#pragma unroll
  for (int k = 0; k < NN / 64; ++k) {
    int i = lane + 64 * k;
    asg_out[i] = asg[i];
  }
}

// ---------- Stage 5: emit boolean as INT32 0/1, row-major [Q][N] ----------

__global__ void k_out(const int* __restrict__ asg, int* __restrict__ out, int total) {
  int t = blockIdx.x * blockDim.x + threadIdx.x;
  if (t >= total) return;
  int q = t / NN;
  int n = t - q * NN;
  out[t] = (asg[n] == q) ? 1 : 0;
}

extern "C" void kernel_launch(void* const* d_in, const int* in_sizes, int n_in,
                              void* d_out, int out_size, void* d_ws, size_t ws_size,
                              hipStream_t stream) {
  const float* logits  = (const float*)d_in[0];  // [32,512,92]
  const float* pboxes  = (const float*)d_in[1];  // [32,512,4]
  const float* tboxes  = (const float*)d_in[2];  // [768,4]
  const int*   tlabels = (const int*)d_in[3];    // [768]

  float* B    = (float*)d_ws;            // 393216 f32, column-major [N][Q]
  float* mx   = B + QN * NN;             // 16384
  float* sm   = mx + BSZ * QN;           // 16384
  float* ad   = sm + BSZ * QN;           // 768
  int*   am   = (int*)(ad + NN);         // 768
  int*   asgg = am + NN;                 // 768
  int*   out  = (int*)d_out;

  hipLaunchKernelGGL(k_softmax_stats, dim3((BSZ * QN) / 256), dim3(256), 0, stream,
                     logits, mx, sm);
  hipLaunchKernelGGL(k_build, dim3((QN * NN) / 256), dim3(256), 0, stream,
                     logits, pboxes, tboxes, tlabels, mx, sm, B);
  hipLaunchKernelGGL(k_init, dim3(NN / 4), dim3(256), 0, stream, B, ad, am);
  hipLaunchKernelGGL(k_scan, dim3(1), dim3(64), 0, stream, B, ad, am, asgg);
  hipLaunchKernelGGL(k_out, dim3((QN * NN) / 256), dim3(256), 0, stream,
                     asgg, out, QN * NN);
}

// Round 5
// 626.284 us; speedup vs baseline: 3.9617x; 1.0665x over previous
//
#include <hip/hip_runtime.h>
#include <math.h>

#pragma clang fp contract(off)

#define QN   512   // queries per image
#define NN   768   // total targets (bs*T)
#define BSZ  32    // batch
#define TPI  24    // targets per image
#define NCLS 92    // classes

// ---------- XLA-faithful special functions (verified bit-exact, round 2) ----------

__device__ __forceinline__ float xla_erf_f32(float x) {
#pragma clang fp contract(off)
  float x2 = x * x;
  float p = -2.72614225801306e-10f;
  p = fmaf(x2, p, 2.77068142495902e-08f);
  p = fmaf(x2, p, -2.10102402082508e-06f);
  p = fmaf(x2, p, -5.69250639462346e-05f);
  p = fmaf(x2, p, -7.34990630326855e-04f);
  p = fmaf(x2, p, -2.95459980854025e-03f);
  p = fmaf(x2, p, -1.60960333262415e-02f);
  p = x * p;
  float q = -1.45660718464996e-05f;
  q = fmaf(x2, q, -2.13374055278905e-04f);
  q = fmaf(x2, q, -1.68282697438203e-03f);
  q = fmaf(x2, q, -7.37332916720468e-03f);
  q = fmaf(x2, q, -1.42647390514189e-02f);
  float r = p / q;
  if (fabsf(x) >= 3.832506856900711f) r = copysignf(1.0f, x);
  return r;
}

__device__ __forceinline__ float xla_erfinv_f32(float b) {
#pragma clang fp contract(off)
  float bb = b * b;
  float u = (-bb) + 1.0f;
  float w = -((float)log((double)u));
  float p;
  if (w < 5.0f) {
    float ww = w - 2.5f;
    p = 2.81022636e-08f;
    p = p * ww + 3.43273939e-07f;
    p = p * ww - 3.5233877e-06f;
    p = p * ww - 4.39150654e-06f;
    p = p * ww + 0.00021858087f;
    p = p * ww - 0.00125372503f;
    p = p * ww - 0.00417768164f;
    p = p * ww + 0.246640727f;
    p = p * ww + 1.50140941f;
  } else {
    float ww = (float)sqrt((double)w) - 3.0f;
    p = -0.000200214257f;
    p = p * ww + 0.000100950558f;
    p = p * ww + 0.00134934322f;
    p = p * ww - 0.00367342844f;
    p = p * ww + 0.00573950773f;
    p = p * ww - 0.0076224613f;
    p = p * ww + 0.00943887047f;
    p = p * ww + 1.00167406f;
    p = p * ww + 2.83297682f;
  }
  return p * b;
}

// ---------- Stage 1: softmax stats ----------

__global__ void k_softmax_stats(const float* __restrict__ logits,
                                float* __restrict__ mx, float* __restrict__ sm) {
#pragma clang fp contract(off)
  int r = blockIdx.x * blockDim.x + threadIdx.x;
  if (r >= BSZ * QN) return;
  const float* row = logits + (size_t)r * NCLS;
  float m = -INFINITY;
  for (int j = 0; j < NCLS; ++j) m = fmaxf(m, row[j]);
  float s = 0.0f;
  for (int j = 0; j < NCLS; ++j) s += expf(row[j] - m);
  mx[r] = m;
  sm[r] = s;
}

// ---------- Stage 2: build B column-major [N][Q] ----------

__global__ void k_build(const float* __restrict__ logits,
                        const float* __restrict__ pboxes,
                        const float* __restrict__ tboxes,
                        const int* __restrict__ tlabels,
                        const float* __restrict__ mx,
                        const float* __restrict__ sm,
                        float* __restrict__ B) {
#pragma clang fp contract(off)
  int t = blockIdx.x * blockDim.x + threadIdx.x;
  if (t >= QN * NN) return;
  int n = t >> 9;
  int q = t & (QN - 1);
  int b = n / TPI;
  int r = b * QN + q;

  int lab = tlabels[n];
  float pc = expf(logits[(size_t)r * NCLS + lab] - mx[r]) / sm[r];
  float cost_class = -pc;

  float4 pb = ((const float4*)pboxes)[r];
  float4 tb = ((const float4*)tboxes)[n];

  float cost_bbox = ((fabsf(pb.x - tb.x) + fabsf(pb.y - tb.y)) +
                     fabsf(pb.z - tb.z)) + fabsf(pb.w - tb.w);

  float p0 = pb.x - 0.5f * pb.z;
  float p1 = pb.y - 0.5f * pb.w;
  float p2 = pb.x + 0.5f * pb.z;
  float p3 = pb.y + 0.5f * pb.w;
  float t0 = tb.x - 0.5f * tb.z;
  float t1 = tb.y - 0.5f * tb.w;
  float t2 = tb.x + 0.5f * tb.z;
  float t3 = tb.y + 0.5f * tb.w;

  float area1 = (p2 - p0) * (p3 - p1);
  float area2 = (t2 - t0) * (t3 - t1);
  float ltx = fmaxf(p0, t0), lty = fmaxf(p1, t1);
  float rbx = fminf(p2, t2), rby = fminf(p3, t3);
  float whx = fmaxf(rbx - ltx, 0.0f), why = fmaxf(rby - lty, 0.0f);
  float inter = whx * why;
  float uni = (area1 + area2) - inter;
  float iou = inter / uni;
  float l2x = fminf(p0, t0), l2y = fminf(p1, t1);
  float r2x = fmaxf(p2, t2), r2y = fmaxf(p3, t3);
  float w2x = fmaxf(r2x - l2x, 0.0f), w2y = fmaxf(r2y - l2y, 0.0f);
  float area = w2x * w2y;
  float giou = iou - (area - uni) / area;

  float C = (cost_bbox + cost_class) + (-giou);

  float z = (-C + 5.5f) / 3.5355339059327378f;
  float prob = 0.5f * (1.0f + xla_erf_f32(z));
  float fx = 0.4242640687119285f * xla_erfinv_f32(prob);

  B[t] = fx;
}

// ---------- Stage 3: per-column init: gap (clamped top2) + raw argmax ----------

__global__ void k_init(const float* __restrict__ B, float* __restrict__ ad,
                       int* __restrict__ am) {
  int n = blockIdx.x * 4 + (threadIdx.x >> 6);   // one wave per column
  int lane = threadIdx.x & 63;
  const float* cp = B + (size_t)n * QN;
  float v1 = -INFINITY, v2 = -INFINITY, bv = -INFINITY;
  int bi = QN;
#pragma unroll
  for (int k = 0; k < QN / 64; ++k) {
    float raw = cp[lane + 64 * k];
    float v = fminf(raw, 100.0f);
    if (v > v1) { v2 = v1; v1 = v; }
    else if (v > v2) v2 = v;
    if (raw > bv) { bv = raw; bi = lane + 64 * k; }
  }
  for (int off = 32; off > 0; off >>= 1) {
    float o1 = __shfl_xor(v1, off), o2 = __shfl_xor(v2, off);
    float ov = __shfl_xor(bv, off); int oi = __shfl_xor(bi, off);
    if (o1 > v1) { v2 = fmaxf(v1, o2); v1 = o1; }
    else v2 = fmaxf(v2, o1);
    if (ov > bv || (ov == bv && oi < bi)) { bv = ov; bi = oi; }
  }
  if (lane == 0) { ad[n] = v1 - v2; am[n] = bi; }
}

// ---------- Stage 4 helpers ----------

__device__ __forceinline__ void wave_maxcount(const float* arr, int lane, float bound,
                                              float& mx, int& cnt) {
  float m = -INFINITY; int c = 0;
#pragma unroll
  for (int k = 0; k < QN / 64; ++k) {
    float v = fminf(arr[lane + 64 * k], 100.0f);
    if (v < bound) {
      if (v > m) { m = v; c = 1; }
      else if (v == m) c++;
    }
  }
  for (int off = 32; off > 0; off >>= 1) {
    float om = __shfl_xor(m, off);
    int oc = __shfl_xor(c, off);
    if (om > m) { m = om; c = oc; }
    else if (om == m) c += oc;
  }
  mx = m; cnt = c;
}

__device__ __forceinline__ int wave_argmax(const float* arr, int lane) {
  float bv = -INFINITY; int bi = 0x7fffffff;
#pragma unroll
  for (int k = 0; k < QN / 64; ++k) {
    float v = arr[lane + 64 * k];
    if (v > bv) { bv = v; bi = lane + 64 * k; }
  }
  for (int off = 32; off > 0; off >>= 1) {
    float ov = __shfl_xor(bv, off);
    int oi = __shfl_xor(bi, off);
    if (ov > bv || (ov == bv && oi < bi)) { bv = ov; bi = oi; }
  }
  return bi;
}

// Multiset top-2; apply "remove x, insert 0". True -> rescan needed.
__device__ __forceinline__ bool ms_update(float x, float& a1, int& c1, float& a2, int& c2) {
  x = fminf(x, 100.0f);
  bool rescan = false;
  if (x == a1) {
    if (--c1 == 0) rescan = true;
  } else if (x == a2) {
    if (--c2 == 0) rescan = true;
  }
  if (!rescan) {
    if (0.0f > a1) { a2 = a1; c2 = c1; a1 = 0.0f; c1 = 1; }
    else if (0.0f == a1) c1++;
    else if (0.0f > a2) { a2 = 0.0f; c2 = 1; }
    else if (0.0f == a2) c2++;
  }
  return rescan;
}

// ---------- Stage 4: single-wave scan, presorted gaps + static payloads ----------
// Pops (col>=2) occur in descending-sorted order of the static initial gaps.
// x0/x1 at pop time derive from registers:
//   - first-touch-among-pops: static bit (minpos over sorted positions)
//   - col-1 pick touches one row, at most once (gap1==0 forever after)
//   - col-0 trivial re-picks only occur once remaining keys are all zero,
//     after which no pops follow (their touches are never consulted)
//   - post-trivial mirrors are {0..., -1e-7 @ negpos}

__global__ void __launch_bounds__(64) k_scan(const float* __restrict__ B,
                                             const float* __restrict__ ad_g,
                                             const int* __restrict__ am_g,
                                             int* __restrict__ asg_out) {
  __shared__ unsigned long long skey[1024];
  __shared__ unsigned long long spay[1024];
  __shared__ float m0[QN];
  __shared__ float m1[QN];
  __shared__ int   asg[NN];
  __shared__ int   minpos[QN];
  const int lane = threadIdx.x;

#pragma unroll
  for (int k = 0; k < QN / 64; ++k) {
    m0[lane + 64 * k] = B[lane + 64 * k];
    m1[lane + 64 * k] = B[QN + lane + 64 * k];
    minpos[lane + 64 * k] = 0x7fffffff;
  }
#pragma unroll
  for (int k = 0; k < NN / 64; ++k) {
    int n = lane + 64 * k;
    asg[n] = -1;
    unsigned long long key = 0ull;
    if (n >= 2) {
      unsigned vb = __float_as_uint(ad_g[n]);      // ad >= 0: bits monotone
      unsigned lo = ((unsigned)(1023 - n) << 16) | (unsigned)am_g[n];
      key = ((unsigned long long)vb << 32) | (unsigned long long)lo;
    }
    skey[n] = key;
  }
#pragma unroll
  for (int k = NN / 64; k < 1024 / 64; ++k) skey[lane + 64 * k] = 0ull;
  __syncthreads();

  // bitonic sort (descending), active pairs only
  for (int kk = 2; kk <= 1024; kk <<= 1) {
    for (int j = kk >> 1; j > 0; j >>= 1) {
#pragma unroll
      for (int k = 0; k < 8; ++k) {
        int g = lane + 64 * k;                      // 512 pairs
        int t = ((g & ~(j - 1)) << 1) | (g & (j - 1));
        int l = t | j;
        unsigned long long a = skey[t], b = skey[l];
        bool sw = ((t & kk) == 0) ? (a < b) : (a > b);
        if (sw) { skey[t] = b; skey[l] = a; }
      }
      __syncthreads();
    }
  }

  // payload gather (pristine mirrors) + first-touch marking
#pragma unroll
  for (int k = 0; k < 16; ++k) {
    int pp = lane + 64 * k;
    int r = (int)(skey[pp] & 0x1FF);
    spay[pp] = (unsigned long long)__float_as_uint(m0[r]) |
               ((unsigned long long)__float_as_uint(m1[r]) << 32);
    if (skey[pp] != 0ull) atomicMin(&minpos[r], pp);
  }
  __syncthreads();
#pragma unroll
  for (int k = 0; k < 16; ++k) {
    int pp = lane + 64 * k;
    int r = (int)(skey[pp] & 0x1FF);
    if (skey[pp] != 0ull && minpos[r] == pp) skey[pp] |= 0x8000ull;
  }
  __syncthreads();

  // initial top-2 multiset state for cols 0 and 1
  float a1, a2, b1, b2; int c1, c2, d1, d2;
  wave_maxcount(m0, lane, INFINITY, a1, c1);
  wave_maxcount(m0, lane, a1, a2, c2);
  wave_maxcount(m1, lane, INFINITY, b1, d1);
  wave_maxcount(m1, lane, b1, b2, d2);

  int p = 0;
  unsigned long long k0 = skey[0], k1 = skey[1], k2 = skey[2];
  unsigned long long y0 = spay[0], y1 = spay[1], y2 = spay[2];
  int negpos0 = -1, negpos1 = -1;
  int dt_m0 = -1, dt_m1 = -1;          // row touched by col1 / col0 pick
  bool trivial0 = false, trivial1 = false;
  int asg0 = -1, asg1 = -1;

  for (int it = 0; it < NN; ++it) {
    float gap0 = (c1 >= 2) ? 0.0f : (a1 - a2);
    float gap1 = (d1 >= 2) ? 0.0f : (b1 - b2);
    int col = 0; float best = gap0;
    if (gap1 > best) { best = gap1; col = 1; }
    float cv = __uint_as_float((unsigned)(k0 >> 32));
    unsigned lo = (unsigned)k0;
    if (cv > best) col = 1023 - (int)(lo >> 16);

    if (col >= 2) {
      int row = (int)(lo & 0x1FF);
      bool ft = (lo & 0x8000u) != 0;
      float ix0 = __uint_as_float((unsigned)y0);
      float ix1 = __uint_as_float((unsigned)(y0 >> 32));
      float x0 = trivial0 ? ((row == negpos0) ? -1e-07f : 0.0f)
                          : ((ft && row != dt_m0) ? ix0 : 0.0f);
      float x1 = trivial1 ? ((row == negpos1) ? -1e-07f : 0.0f)
                          : ((ft && row != dt_m1) ? ix1 : 0.0f);
      if (lane == 0) {
        m0[row] = 0.0f;
        m1[row] = 0.0f;
        asg[col] = row;
      }
      // advance + prefetch depth-2
      k0 = k1; k1 = k2; y0 = y1; y1 = y2;
      ++p;
      k2 = skey[p + 2]; y2 = spay[p + 2];

      if (negpos0 == row) negpos0 = -1;
      if (negpos1 == row) negpos1 = -1;
      if (ms_update(x0, a1, c1, a2, c2)) {
        __syncthreads();
        wave_maxcount(m0, lane, INFINITY, a1, c1);
        wave_maxcount(m0, lane, a1, a2, c2);
      }
      if (ms_update(x1, b1, d1, b2, d2)) {
        __syncthreads();
        wave_maxcount(m1, lane, INFINITY, b1, d1);
        wave_maxcount(m1, lane, b1, b2, d2);
      }
      if (asg0 == row) asg0 = -1;
      if (asg1 == row) asg1 = -1;
    } else if (col == 0) {
      int row;
      if (trivial0) row = (negpos0 == 0) ? 1 : 0;
      else row = wave_argmax(m0, lane);
      float x1 = m1[row];
#pragma unroll
      for (int k = 0; k < QN / 64; ++k) m0[lane + 64 * k] = 0.0f;
      if (lane == 0) {
        m0[row] = -1e-07f;
        m1[row] = 0.0f;
      }
      __syncthreads();
      a1 = 0.0f; c1 = QN - 1; a2 = -1e-07f; c2 = 1;
      trivial0 = true; negpos0 = row;
      dt_m1 = row;                       // m1[row] zeroed by this pick
      if (negpos1 == row) negpos1 = -1;
      if (ms_update(x1, b1, d1, b2, d2)) {
        __syncthreads();
        wave_maxcount(m1, lane, INFINITY, b1, d1);
        wave_maxcount(m1, lane, b1, b2, d2);
      }
      asg0 = row;
      if (asg1 == row) asg1 = -1;
    } else { // col == 1
      int row;
      if (trivial1) row = (negpos1 == 0) ? 1 : 0;
      else row = wave_argmax(m1, lane);
      float x0 = m0[row];
#pragma unroll
      for (int k = 0; k < QN / 64; ++k) m1[lane + 64 * k] = 0.0f;
      if (lane == 0) {
        m1[row] = -1e-07f;
        m0[row] = 0.0f;
      }
      __syncthreads();
      b1 = 0.0f; d1 = QN - 1; b2 = -1e-07f; d2 = 1;
      trivial1 = true; negpos1 = row;
      dt_m0 = row;                       // m0[row] zeroed by this pick
      if (negpos0 == row) negpos0 = -1;
      if (ms_update(x0, a1, c1, a2, c2)) {
        __syncthreads();
        wave_maxcount(m0, lane, INFINITY, a1, c1);
        wave_maxcount(m0, lane, a1, a2, c2);
      }
      asg1 = row;
      if (asg0 == row) asg0 = -1;
    }
  }

  if (lane == 0) { asg[0] = asg0; asg[1] = asg1; }
  __syncthreads();
#pragma unroll
  for (int k = 0; k < NN / 64; ++k) {
    int i = lane + 64 * k;
    asg_out[i] = asg[i];
  }
}

// ---------- Stage 5: emit boolean as INT32 0/1, row-major [Q][N] ----------

__global__ void k_out(const int* __restrict__ asg, int* __restrict__ out, int total) {
  int t = blockIdx.x * blockDim.x + threadIdx.x;
  if (t >= total) return;
  int q = t / NN;
  int n = t - q * NN;
  out[t] = (asg[n] == q) ? 1 : 0;
}

extern "C" void kernel_launch(void* const* d_in, const int* in_sizes, int n_in,
                              void* d_out, int out_size, void* d_ws, size_t ws_size,
                              hipStream_t stream) {
  const float* logits  = (const float*)d_in[0];  // [32,512,92]
  const float* pboxes  = (const float*)d_in[1];  // [32,512,4]
  const float* tboxes  = (const float*)d_in[2];  // [768,4]
  const int*   tlabels = (const int*)d_in[3];    // [768]

  float* B    = (float*)d_ws;            // 393216 f32, column-major [N][Q]
  float* mx   = B + QN * NN;             // 16384
  float* sm   = mx + BSZ * QN;           // 16384
  float* ad   = sm + BSZ * QN;           // 768
  int*   am   = (int*)(ad + NN);         // 768
  int*   asgg = am + NN;                 // 768
  int*   out  = (int*)d_out;

  hipLaunchKernelGGL(k_softmax_stats, dim3((BSZ * QN) / 256), dim3(256), 0, stream,
                     logits, mx, sm);
  hipLaunchKernelGGL(k_build, dim3((QN * NN) / 256), dim3(256), 0, stream,
                     logits, pboxes, tboxes, tlabels, mx, sm, B);
  hipLaunchKernelGGL(k_init, dim3(NN / 4), dim3(256), 0, stream, B, ad, am);
  hipLaunchKernelGGL(k_scan, dim3(1), dim3(64), 0, stream, B, ad, am, asgg);
  hipLaunchKernelGGL(k_out, dim3((QN * NN) / 256), dim3(256), 0, stream,
                     asgg, out, QN * NN);
}

// Round 6
// 93.599 us; speedup vs baseline: 26.5083x; 6.6911x over previous
//
#include <hip/hip_runtime.h>
#include <math.h>

#pragma clang fp contract(off)

#define QN   512   // queries per image
#define NN   768   // total targets (bs*T)
#define BSZ  32    // batch
#define TPI  24    // targets per image
#define NCLS 92    // classes

// ---------- XLA-faithful special functions (verified bit-exact, round 2) ----------

__device__ __forceinline__ float xla_erf_f32(float x) {
#pragma clang fp contract(off)
  float x2 = x * x;
  float p = -2.72614225801306e-10f;
  p = fmaf(x2, p, 2.77068142495902e-08f);
  p = fmaf(x2, p, -2.10102402082508e-06f);
  p = fmaf(x2, p, -5.69250639462346e-05f);
  p = fmaf(x2, p, -7.34990630326855e-04f);
  p = fmaf(x2, p, -2.95459980854025e-03f);
  p = fmaf(x2, p, -1.60960333262415e-02f);
  p = x * p;
  float q = -1.45660718464996e-05f;
  q = fmaf(x2, q, -2.13374055278905e-04f);
  q = fmaf(x2, q, -1.68282697438203e-03f);
  q = fmaf(x2, q, -7.37332916720468e-03f);
  q = fmaf(x2, q, -1.42647390514189e-02f);
  float r = p / q;
  if (fabsf(x) >= 3.832506856900711f) r = copysignf(1.0f, x);
  return r;
}

__device__ __forceinline__ float xla_erfinv_f32(float b) {
#pragma clang fp contract(off)
  float bb = b * b;
  float u = (-bb) + 1.0f;
  float w = -((float)log((double)u));
  float p;
  if (w < 5.0f) {
    float ww = w - 2.5f;
    p = 2.81022636e-08f;
    p = p * ww + 3.43273939e-07f;
    p = p * ww - 3.5233877e-06f;
    p = p * ww - 4.39150654e-06f;
    p = p * ww + 0.00021858087f;
    p = p * ww - 0.00125372503f;
    p = p * ww - 0.00417768164f;
    p = p * ww + 0.246640727f;
    p = p * ww + 1.50140941f;
  } else {
    float ww = (float)sqrt((double)w) - 3.0f;
    p = -0.000200214257f;
    p = p * ww + 0.000100950558f;
    p = p * ww + 0.00134934322f;
    p = p * ww - 0.00367342844f;
    p = p * ww + 0.00573950773f;
    p = p * ww - 0.0076224613f;
    p = p * ww + 0.00943887047f;
    p = p * ww + 1.00167406f;
    p = p * ww + 2.83297682f;
  }
  return p * b;
}

// ---------- Stage 1: softmax stats ----------

__global__ void k_softmax_stats(const float* __restrict__ logits,
                                float* __restrict__ mx, float* __restrict__ sm) {
#pragma clang fp contract(off)
  int r = blockIdx.x * blockDim.x + threadIdx.x;
  if (r >= BSZ * QN) return;
  const float* row = logits + (size_t)r * NCLS;
  float m = -INFINITY;
  for (int j = 0; j < NCLS; ++j) m = fmaxf(m, row[j]);
  float s = 0.0f;
  for (int j = 0; j < NCLS; ++j) s += expf(row[j] - m);
  mx[r] = m;
  sm[r] = s;
}

// ---------- Stage 2: build B column-major [N][Q] ----------

__global__ void k_build(const float* __restrict__ logits,
                        const float* __restrict__ pboxes,
                        const float* __restrict__ tboxes,
                        const int* __restrict__ tlabels,
                        const float* __restrict__ mx,
                        const float* __restrict__ sm,
                        float* __restrict__ B) {
#pragma clang fp contract(off)
  int t = blockIdx.x * blockDim.x + threadIdx.x;
  if (t >= QN * NN) return;
  int n = t >> 9;
  int q = t & (QN - 1);
  int b = n / TPI;
  int r = b * QN + q;

  int lab = tlabels[n];
  float pc = expf(logits[(size_t)r * NCLS + lab] - mx[r]) / sm[r];
  float cost_class = -pc;

  float4 pb = ((const float4*)pboxes)[r];
  float4 tb = ((const float4*)tboxes)[n];

  float cost_bbox = ((fabsf(pb.x - tb.x) + fabsf(pb.y - tb.y)) +
                     fabsf(pb.z - tb.z)) + fabsf(pb.w - tb.w);

  float p0 = pb.x - 0.5f * pb.z;
  float p1 = pb.y - 0.5f * pb.w;
  float p2 = pb.x + 0.5f * pb.z;
  float p3 = pb.y + 0.5f * pb.w;
  float t0 = tb.x - 0.5f * tb.z;
  float t1 = tb.y - 0.5f * tb.w;
  float t2 = tb.x + 0.5f * tb.z;
  float t3 = tb.y + 0.5f * tb.w;

  float area1 = (p2 - p0) * (p3 - p1);
  float area2 = (t2 - t0) * (t3 - t1);
  float ltx = fmaxf(p0, t0), lty = fmaxf(p1, t1);
  float rbx = fminf(p2, t2), rby = fminf(p3, t3);
  float whx = fmaxf(rbx - ltx, 0.0f), why = fmaxf(rby - lty, 0.0f);
  float inter = whx * why;
  float uni = (area1 + area2) - inter;
  float iou = inter / uni;
  float l2x = fminf(p0, t0), l2y = fminf(p1, t1);
  float r2x = fmaxf(p2, t2), r2y = fmaxf(p3, t3);
  float w2x = fmaxf(r2x - l2x, 0.0f), w2y = fmaxf(r2y - l2y, 0.0f);
  float area = w2x * w2y;
  float giou = iou - (area - uni) / area;

  float C = (cost_bbox + cost_class) + (-giou);

  float z = (-C + 5.5f) / 3.5355339059327378f;
  float prob = 0.5f * (1.0f + xla_erf_f32(z));
  float fx = 0.4242640687119285f * xla_erfinv_f32(prob);

  B[t] = fx;
}

// ---------- Stage 3: per-column init: gap (clamped top2) + raw argmax ----------

__global__ void k_init(const float* __restrict__ B, float* __restrict__ ad,
                       int* __restrict__ am) {
  int n = blockIdx.x * 4 + (threadIdx.x >> 6);   // one wave per column
  int lane = threadIdx.x & 63;
  const float* cp = B + (size_t)n * QN;
  float v1 = -INFINITY, v2 = -INFINITY, bv = -INFINITY;
  int bi = QN;
#pragma unroll
  for (int k = 0; k < QN / 64; ++k) {
    float raw = cp[lane + 64 * k];
    float v = fminf(raw, 100.0f);
    if (v > v1) { v2 = v1; v1 = v; }
    else if (v > v2) v2 = v;
    if (raw > bv) { bv = raw; bi = lane + 64 * k; }
  }
  for (int off = 32; off > 0; off >>= 1) {
    float o1 = __shfl_xor(v1, off), o2 = __shfl_xor(v2, off);
    float ov = __shfl_xor(bv, off); int oi = __shfl_xor(bi, off);
    if (o1 > v1) { v2 = fmaxf(v1, o2); v1 = o1; }
    else v2 = fmaxf(v2, o1);
    if (ov > bv || (ov == bv && oi < bi)) { bv = ov; bi = oi; }
  }
  if (lane == 0) { ad[n] = v1 - v2; am[n] = bi; }
}

// ---------- Stage 4 helpers ----------

__device__ __forceinline__ void wave_maxcount(const float* arr, int lane, float bound,
                                              float& mx, int& cnt) {
  float m = -INFINITY; int c = 0;
#pragma unroll
  for (int k = 0; k < QN / 64; ++k) {
    float v = fminf(arr[lane + 64 * k], 100.0f);
    if (v < bound) {
      if (v > m) { m = v; c = 1; }
      else if (v == m) c++;
    }
  }
  for (int off = 32; off > 0; off >>= 1) {
    float om = __shfl_xor(m, off);
    int oc = __shfl_xor(c, off);
    if (om > m) { m = om; c = oc; }
    else if (om == m) c += oc;
  }
  mx = m; cnt = c;
}

__device__ __forceinline__ int wave_argmax(const float* arr, int lane) {
  float bv = -INFINITY; int bi = 0x7fffffff;
#pragma unroll
  for (int k = 0; k < QN / 64; ++k) {
    float v = arr[lane + 64 * k];
    if (v > bv) { bv = v; bi = lane + 64 * k; }
  }
  for (int off = 32; off > 0; off >>= 1) {
    float ov = __shfl_xor(bv, off);
    int oi = __shfl_xor(bi, off);
    if (ov > bv || (ov == bv && oi < bi)) { bv = ov; bi = oi; }
  }
  return bi;
}

// Multiset top-2; apply "remove x, insert 0". True -> rescan needed.
__device__ __forceinline__ bool ms_update(float x, float& a1, int& c1, float& a2, int& c2) {
  x = fminf(x, 100.0f);
  bool rescan = false;
  if (x == a1) {
    if (--c1 == 0) rescan = true;
  } else if (x == a2) {
    if (--c2 == 0) rescan = true;
  }
  if (!rescan) {
    if (0.0f > a1) { a2 = a1; c2 = c1; a1 = 0.0f; c1 = 1; }
    else if (0.0f == a1) c1++;
    else if (0.0f > a2) { a2 = 0.0f; c2 = 1; }
    else if (0.0f == a2) c2++;
  }
  return rescan;
}

// ---------- Stage 4: single-wave scan, 64-wide batched pops ----------
// Pops are no-ops on the tracked scalar state unless the popped value hits
// the current top-2 of m0/m1 (x==a1||x==a2) or a trivial-state marker
// (x!=0). Selection events occur when cv <= max(gap0,gap1). Both are found
// via one ballot each; clean prefixes of up to 64 pops apply in bulk.
// Event handling replicates the validated round-5 scalar code exactly.

__global__ void __launch_bounds__(64) k_scan(const float* __restrict__ B,
                                             const float* __restrict__ ad_g,
                                             const int* __restrict__ am_g,
                                             int* __restrict__ asg_out) {
  __shared__ unsigned long long skey[1024];
  __shared__ unsigned long long spay[1024];
  __shared__ float m0[QN];
  __shared__ float m1[QN];
  __shared__ int   asg[NN];
  __shared__ int   minpos[QN];
  const int lane = threadIdx.x;

#pragma unroll
  for (int k = 0; k < QN / 64; ++k) {
    m0[lane + 64 * k] = B[lane + 64 * k];
    m1[lane + 64 * k] = B[QN + lane + 64 * k];
    minpos[lane + 64 * k] = 0x7fffffff;
  }
#pragma unroll
  for (int k = 0; k < NN / 64; ++k) {
    int n = lane + 64 * k;
    asg[n] = -1;
    unsigned long long key = 0ull;
    if (n >= 2) {
      unsigned vb = __float_as_uint(ad_g[n]);      // ad >= 0: bits monotone
      unsigned lo = ((unsigned)(1023 - n) << 16) | (unsigned)am_g[n];
      key = ((unsigned long long)vb << 32) | (unsigned long long)lo;
    }
    skey[n] = key;
  }
#pragma unroll
  for (int k = NN / 64; k < 1024 / 64; ++k) skey[lane + 64 * k] = 0ull;
  __syncthreads();

  // bitonic sort (descending), active pairs only
  for (int kk = 2; kk <= 1024; kk <<= 1) {
    for (int j = kk >> 1; j > 0; j >>= 1) {
#pragma unroll
      for (int k = 0; k < 8; ++k) {
        int g = lane + 64 * k;                      // 512 pairs
        int t = ((g & ~(j - 1)) << 1) | (g & (j - 1));
        int l = t | j;
        unsigned long long a = skey[t], b = skey[l];
        bool sw = ((t & kk) == 0) ? (a < b) : (a > b);
        if (sw) { skey[t] = b; skey[l] = a; }
      }
      __syncthreads();
    }
  }

  // payload gather (clamped pristine mirrors) + first-touch marking
#pragma unroll
  for (int k = 0; k < 16; ++k) {
    int pp = lane + 64 * k;
    int r = (int)(skey[pp] & 0x1FF);
    spay[pp] = (unsigned long long)__float_as_uint(fminf(m0[r], 100.0f)) |
               ((unsigned long long)__float_as_uint(fminf(m1[r], 100.0f)) << 32);
    if (skey[pp] != 0ull) atomicMin(&minpos[r], pp);
  }
  __syncthreads();
#pragma unroll
  for (int k = 0; k < 16; ++k) {
    int pp = lane + 64 * k;
    int r = (int)(skey[pp] & 0x1FF);
    if (skey[pp] != 0ull && minpos[r] == pp) skey[pp] |= 0x8000ull;
  }
  __syncthreads();

  // initial top-2 multiset state for cols 0 and 1
  float a1, a2, b1, b2; int c1, c2, d1, d2;
  wave_maxcount(m0, lane, INFINITY, a1, c1);
  wave_maxcount(m0, lane, a1, a2, c2);
  wave_maxcount(m1, lane, INFINITY, b1, d1);
  wave_maxcount(m1, lane, b1, b2, d2);

  int p = 0, it = 0;
  int negpos0 = -1, negpos1 = -1;
  int dt_m0 = -1, dt_m1 = -1;
  bool trivial0 = false, trivial1 = false;
  int asg0 = -1, asg1 = -1;

  while (it < NN) {
    float gap0 = (c1 >= 2) ? 0.0f : (a1 - a2);
    float gap1 = (d1 >= 2) ? 0.0f : (b1 - b2);
    float best = fmaxf(gap0, gap1);

    unsigned long long kk = skey[p + lane];
    unsigned long long yy = spay[p + lane];
    float cv = __uint_as_float((unsigned)(kk >> 32));
    unsigned lo = (unsigned)kk;
    int row = (int)(lo & 0x1FF);
    bool ft = (lo & 0x8000u) != 0;
    float ix0 = __uint_as_float((unsigned)yy);
    float ix1 = __uint_as_float((unsigned)(yy >> 32));

    float x0 = trivial0 ? ((row == negpos0) ? -1e-07f : 0.0f)
                        : ((ft && row != dt_m0) ? ix0 : 0.0f);
    float x1 = trivial1 ? ((row == negpos1) ? -1e-07f : 0.0f)
                        : ((ft && row != dt_m1) ? ix1 : 0.0f);

    bool slow0 = (!trivial0) && !(a1 > 0.0f && a2 > 0.0f);
    bool slow1 = (!trivial1) && !(b1 > 0.0f && b2 > 0.0f);
    bool ev = slow0 || slow1 ||
              (trivial0 ? (x0 != 0.0f) : (x0 == a1 || x0 == a2)) ||
              (trivial1 ? (x1 != 0.0f) : (x1 == b1 || x1 == b2));

    unsigned long long selm = __ballot(!(cv > best));
    unsigned long long evm  = __ballot(ev);
    int ssel = selm ? (int)__builtin_ctzll(selm) : 64;
    int sev  = evm  ? (int)__builtin_ctzll(evm)  : 64;
    int rem = NN - it;
    int bound = (rem < 64) ? rem : 64;
    int pref = (ssel < sev) ? ssel : sev;
    if (pref > bound) pref = bound;

    if (lane < pref) {                       // bulk-apply clean pops
      m0[row] = 0.0f;
      m1[row] = 0.0f;
      asg[1023 - (int)(lo >> 16)] = row;
    }
    if (pref > 0) {
      unsigned long long pm = (pref >= 64) ? ~0ull : ((1ull << pref) - 1ull);
      if (__ballot(row == asg0) & pm) asg0 = -1;   // provably never fires; insurance
      if (__ballot(row == asg1) & pm) asg1 = -1;
      p += pref; it += pref;
    }
    if (pref == bound) continue;

    __syncthreads();                         // prefix m0/m1 writes visible
    int e = pref;
    if (ssel <= sev) {
      // ---- selection event: col 0 or col 1 pick ----
      int col = (gap1 > gap0) ? 1 : 0;
      if (col == 0) {
        int rw = trivial0 ? ((negpos0 == 0) ? 1 : 0) : wave_argmax(m0, lane);
        float x1p = m1[rw];
#pragma unroll
        for (int k = 0; k < QN / 64; ++k) m0[lane + 64 * k] = 0.0f;
        if (lane == 0) { m0[rw] = -1e-07f; m1[rw] = 0.0f; }
        __syncthreads();
        a1 = 0.0f; c1 = QN - 1; a2 = -1e-07f; c2 = 1;
        trivial0 = true; negpos0 = rw;
        dt_m1 = rw;
        if (negpos1 == rw) negpos1 = -1;
        if (ms_update(x1p, b1, d1, b2, d2)) {
          __syncthreads();
          wave_maxcount(m1, lane, INFINITY, b1, d1);
          wave_maxcount(m1, lane, b1, b2, d2);
        }
        asg0 = rw;
        if (asg1 == rw) asg1 = -1;
      } else {
        int rw = trivial1 ? ((negpos1 == 0) ? 1 : 0) : wave_argmax(m1, lane);
        float x0p = m0[rw];
#pragma unroll
        for (int k = 0; k < QN / 64; ++k) m1[lane + 64 * k] = 0.0f;
        if (lane == 0) { m1[rw] = -1e-07f; m0[rw] = 0.0f; }
        __syncthreads();
        b1 = 0.0f; d1 = QN - 1; b2 = -1e-07f; d2 = 1;
        trivial1 = true; negpos1 = rw;
        dt_m0 = rw;
        if (negpos0 == rw) negpos0 = -1;
        if (ms_update(x0p, a1, c1, a2, c2)) {
          __syncthreads();
          wave_maxcount(m0, lane, INFINITY, a1, c1);
          wave_maxcount(m0, lane, a1, a2, c2);
        }
        asg1 = rw;
        if (asg0 == rw) asg0 = -1;
      }
      ++it;
    } else {
      // ---- multiset event: one scalar pop at sorted position p (lane e) ----
      float cx0 = __shfl(x0, e);
      float cx1 = __shfl(x1, e);
      int crow  = __shfl(row, e);
      int ccol  = 1023 - __shfl((int)(lo >> 16), e);
      if (lane == 0) { m0[crow] = 0.0f; m1[crow] = 0.0f; asg[ccol] = crow; }
      if (negpos0 == crow) negpos0 = -1;
      if (negpos1 == crow) negpos1 = -1;
      if (ms_update(cx0, a1, c1, a2, c2)) {
        __syncthreads();
        wave_maxcount(m0, lane, INFINITY, a1, c1);
        wave_maxcount(m0, lane, a1, a2, c2);
      }
      if (ms_update(cx1, b1, d1, b2, d2)) {
        __syncthreads();
        wave_maxcount(m1, lane, INFINITY, b1, d1);
        wave_maxcount(m1, lane, b1, b2, d2);
      }
      if (asg0 == crow) asg0 = -1;
      if (asg1 == crow) asg1 = -1;
      ++p; ++it;
    }
  }

  if (lane == 0) { asg[0] = asg0; asg[1] = asg1; }
  __syncthreads();
#pragma unroll
  for (int k = 0; k < NN / 64; ++k) {
    int i = lane + 64 * k;
    asg_out[i] = asg[i];
  }
}

// ---------- Stage 5: emit boolean as INT32 0/1, row-major [Q][N] ----------

__global__ void k_out(const int* __restrict__ asg, int* __restrict__ out, int total) {
  int t = blockIdx.x * blockDim.x + threadIdx.x;
  if (t >= total) return;
  int q = t / NN;
  int n = t - q * NN;
  out[t] = (asg[n] == q) ? 1 : 0;
}

extern "C" void kernel_launch(void* const* d_in, const int* in_sizes, int n_in,
                              void* d_out, int out_size, void* d_ws, size_t ws_size,
                              hipStream_t stream) {
  const float* logits  = (const float*)d_in[0];  // [32,512,92]
  const float* pboxes  = (const float*)d_in[1];  // [32,512,4]
  const float* tboxes  = (const float*)d_in[2];  // [768,4]
  const int*   tlabels = (const int*)d_in[3];    // [768]

  float* B    = (float*)d_ws;            // 393216 f32, column-major [N][Q]
  float* mx   = B + QN * NN;             // 16384
  float* sm   = mx + BSZ * QN;           // 16384
  float* ad   = sm + BSZ * QN;           // 768
  int*   am   = (int*)(ad + NN);         // 768
  int*   asgg = am + NN;                 // 768
  int*   out  = (int*)d_out;

  hipLaunchKernelGGL(k_softmax_stats, dim3((BSZ * QN) / 256), dim3(256), 0, stream,
                     logits, mx, sm);
  hipLaunchKernelGGL(k_build, dim3((QN * NN) / 256), dim3(256), 0, stream,
                     logits, pboxes, tboxes, tlabels, mx, sm, B);
  hipLaunchKernelGGL(k_init, dim3(NN / 4), dim3(256), 0, stream, B, ad, am);
  hipLaunchKernelGGL(k_scan, dim3(1), dim3(64), 0, stream, B, ad, am, asgg);
  hipLaunchKernelGGL(k_out, dim3((QN * NN) / 256), dim3(256), 0, stream,
                     asgg, out, QN * NN);
}

// Round 7
// 56.075 us; speedup vs baseline: 44.2475x; 1.6692x over previous
//
#include <hip/hip_runtime.h>
#include <math.h>

#pragma clang fp contract(off)

#define QN   512   // queries per image
#define NN   768   // total targets (bs*T)
#define BSZ  32    // batch
#define TPI  24    // targets per image
#define NCLS 92    // classes

// single-wave LDS fence: order this wave's ds_writes before its ds_reads
#define WFENCE() asm volatile("s_waitcnt lgkmcnt(0)" ::: "memory")

// ---------- XLA-faithful special functions (verified bit-exact, round 2) ----------

__device__ __forceinline__ float xla_erf_f32(float x) {
#pragma clang fp contract(off)
  float x2 = x * x;
  float p = -2.72614225801306e-10f;
  p = fmaf(x2, p, 2.77068142495902e-08f);
  p = fmaf(x2, p, -2.10102402082508e-06f);
  p = fmaf(x2, p, -5.69250639462346e-05f);
  p = fmaf(x2, p, -7.34990630326855e-04f);
  p = fmaf(x2, p, -2.95459980854025e-03f);
  p = fmaf(x2, p, -1.60960333262415e-02f);
  p = x * p;
  float q = -1.45660718464996e-05f;
  q = fmaf(x2, q, -2.13374055278905e-04f);
  q = fmaf(x2, q, -1.68282697438203e-03f);
  q = fmaf(x2, q, -7.37332916720468e-03f);
  q = fmaf(x2, q, -1.42647390514189e-02f);
  float r = p / q;
  if (fabsf(x) >= 3.832506856900711f) r = copysignf(1.0f, x);
  return r;
}

__device__ __forceinline__ float xla_erfinv_f32(float b) {
#pragma clang fp contract(off)
  float bb = b * b;
  float u = (-bb) + 1.0f;
  float w = -((float)log((double)u));
  float p;
  if (w < 5.0f) {
    float ww = w - 2.5f;
    p = 2.81022636e-08f;
    p = p * ww + 3.43273939e-07f;
    p = p * ww - 3.5233877e-06f;
    p = p * ww - 4.39150654e-06f;
    p = p * ww + 0.00021858087f;
    p = p * ww - 0.00125372503f;
    p = p * ww - 0.00417768164f;
    p = p * ww + 0.246640727f;
    p = p * ww + 1.50140941f;
  } else {
    float ww = (float)sqrt((double)w) - 3.0f;
    p = -0.000200214257f;
    p = p * ww + 0.000100950558f;
    p = p * ww + 0.00134934322f;
    p = p * ww - 0.00367342844f;
    p = p * ww + 0.00573950773f;
    p = p * ww - 0.0076224613f;
    p = p * ww + 0.00943887047f;
    p = p * ww + 1.00167406f;
    p = p * ww + 2.83297682f;
  }
  return p * b;
}

// ---------- Stage 1: softmax stats (LDS-staged; identical sequential math) ----------

#define SROWS 64

__global__ void __launch_bounds__(256) k_softmax_stats(const float* __restrict__ logits,
                                                       float* __restrict__ mx,
                                                       float* __restrict__ sm) {
#pragma clang fp contract(off)
  __shared__ float buf[SROWS][NCLS + 1];   // +1 pad: conflict-free row reads
  int r0 = blockIdx.x * SROWS;
  const float* src = logits + (size_t)r0 * NCLS;
  for (int i = threadIdx.x; i < SROWS * NCLS; i += 256) {
    int rr = i / NCLS, cc = i - rr * NCLS;
    buf[rr][cc] = src[i];
  }
  __syncthreads();
  int r = threadIdx.x;
  if (r < SROWS) {
    const float* row = buf[r];
    float m = -INFINITY;
    for (int j = 0; j < NCLS; ++j) m = fmaxf(m, row[j]);
    float s = 0.0f;
    for (int j = 0; j < NCLS; ++j) s += expf(row[j] - m);
    mx[r0 + r] = m;
    sm[r0 + r] = s;
  }
}

// ---------- Stage 2: build B column-major [N][Q] ----------

__global__ void k_build(const float* __restrict__ logits,
                        const float* __restrict__ pboxes,
                        const float* __restrict__ tboxes,
                        const int* __restrict__ tlabels,
                        const float* __restrict__ mx,
                        const float* __restrict__ sm,
                        float* __restrict__ B) {
#pragma clang fp contract(off)
  int t = blockIdx.x * blockDim.x + threadIdx.x;
  if (t >= QN * NN) return;
  int n = t >> 9;
  int q = t & (QN - 1);
  int b = n / TPI;
  int r = b * QN + q;

  int lab = tlabels[n];
  float pc = expf(logits[(size_t)r * NCLS + lab] - mx[r]) / sm[r];
  float cost_class = -pc;

  float4 pb = ((const float4*)pboxes)[r];
  float4 tb = ((const float4*)tboxes)[n];

  float cost_bbox = ((fabsf(pb.x - tb.x) + fabsf(pb.y - tb.y)) +
                     fabsf(pb.z - tb.z)) + fabsf(pb.w - tb.w);

  float p0 = pb.x - 0.5f * pb.z;
  float p1 = pb.y - 0.5f * pb.w;
  float p2 = pb.x + 0.5f * pb.z;
  float p3 = pb.y + 0.5f * pb.w;
  float t0 = tb.x - 0.5f * tb.z;
  float t1 = tb.y - 0.5f * tb.w;
  float t2 = tb.x + 0.5f * tb.z;
  float t3 = tb.y + 0.5f * tb.w;

  float area1 = (p2 - p0) * (p3 - p1);
  float area2 = (t2 - t0) * (t3 - t1);
  float ltx = fmaxf(p0, t0), lty = fmaxf(p1, t1);
  float rbx = fminf(p2, t2), rby = fminf(p3, t3);
  float whx = fmaxf(rbx - ltx, 0.0f), why = fmaxf(rby - lty, 0.0f);
  float inter = whx * why;
  float uni = (area1 + area2) - inter;
  float iou = inter / uni;
  float l2x = fminf(p0, t0), l2y = fminf(p1, t1);
  float r2x = fmaxf(p2, t2), r2y = fmaxf(p3, t3);
  float w2x = fmaxf(r2x - l2x, 0.0f), w2y = fmaxf(r2y - l2y, 0.0f);
  float area = w2x * w2y;
  float giou = iou - (area - uni) / area;

  float C = (cost_bbox + cost_class) + (-giou);

  float z = (-C + 5.5f) / 3.5355339059327378f;
  float prob = 0.5f * (1.0f + xla_erf_f32(z));
  float fx = 0.4242640687119285f * xla_erfinv_f32(prob);

  B[t] = fx;
}

// ---------- Stage 3: per-column init: gap (clamped top2) + raw argmax ----------

__global__ void k_init(const float* __restrict__ B, float* __restrict__ ad,
                       int* __restrict__ am) {
  int n = blockIdx.x * 4 + (threadIdx.x >> 6);   // one wave per column
  int lane = threadIdx.x & 63;
  const float* cp = B + (size_t)n * QN;
  float v1 = -INFINITY, v2 = -INFINITY, bv = -INFINITY;
  int bi = QN;
#pragma unroll
  for (int k = 0; k < QN / 64; ++k) {
    float raw = cp[lane + 64 * k];
    float v = fminf(raw, 100.0f);
    if (v > v1) { v2 = v1; v1 = v; }
    else if (v > v2) v2 = v;
    if (raw > bv) { bv = raw; bi = lane + 64 * k; }
  }
  for (int off = 32; off > 0; off >>= 1) {
    float o1 = __shfl_xor(v1, off), o2 = __shfl_xor(v2, off);
    float ov = __shfl_xor(bv, off); int oi = __shfl_xor(bi, off);
    if (o1 > v1) { v2 = fmaxf(v1, o2); v1 = o1; }
    else v2 = fmaxf(v2, o1);
    if (ov > bv || (ov == bv && oi < bi)) { bv = ov; bi = oi; }
  }
  if (lane == 0) { ad[n] = v1 - v2; am[n] = bi; }
}

// ---------- Stage 4 helpers ----------

__device__ __forceinline__ void wave_maxcount(const float* arr, int lane, float bound,
                                              float& mx, int& cnt) {
  float m = -INFINITY; int c = 0;
#pragma unroll
  for (int k = 0; k < QN / 64; ++k) {
    float v = fminf(arr[lane + 64 * k], 100.0f);
    if (v < bound) {
      if (v > m) { m = v; c = 1; }
      else if (v == m) c++;
    }
  }
  for (int off = 32; off > 0; off >>= 1) {
    float om = __shfl_xor(m, off);
    int oc = __shfl_xor(c, off);
    if (om > m) { m = om; c = oc; }
    else if (om == m) c += oc;
  }
  mx = m; cnt = c;
}

__device__ __forceinline__ int wave_argmax(const float* arr, int lane) {
  float bv = -INFINITY; int bi = 0x7fffffff;
#pragma unroll
  for (int k = 0; k < QN / 64; ++k) {
    float v = arr[lane + 64 * k];
    if (v > bv) { bv = v; bi = lane + 64 * k; }
  }
  for (int off = 32; off > 0; off >>= 1) {
    float ov = __shfl_xor(bv, off);
    int oi = __shfl_xor(bi, off);
    if (ov > bv || (ov == bv && oi < bi)) { bv = ov; bi = oi; }
  }
  return bi;
}

// Multiset top-2; apply "remove x, insert 0". True -> rescan needed.
__device__ __forceinline__ bool ms_update(float x, float& a1, int& c1, float& a2, int& c2) {
  x = fminf(x, 100.0f);
  bool rescan = false;
  if (x == a1) {
    if (--c1 == 0) rescan = true;
  } else if (x == a2) {
    if (--c2 == 0) rescan = true;
  }
  if (!rescan) {
    if (0.0f > a1) { a2 = a1; c2 = c1; a1 = 0.0f; c1 = 1; }
    else if (0.0f == a1) c1++;
    else if (0.0f > a2) { a2 = 0.0f; c2 = 1; }
    else if (0.0f == a2) c2++;
  }
  return rescan;
}

// ---------- Stage 4: 256-thread setup (4-wave sort) + 1-wave windowed scan ----------
// Identical decision algebra to the validated round-6 kernel; only the
// schedule changes: sort/init 4x parallel, then waves 1-3 exit and wave 0
// runs the batched event loop with register-cached 64-key windows and
// intra-wave lgkmcnt fences instead of barriers.

__global__ void __launch_bounds__(256) k_scan(const float* __restrict__ B,
                                              const float* __restrict__ ad_g,
                                              const int* __restrict__ am_g,
                                              int* __restrict__ asg_out) {
  __shared__ unsigned long long skey[1024];
  __shared__ unsigned long long spay[1024];
  __shared__ float m0[QN];
  __shared__ float m1[QN];
  __shared__ int   asg[NN];
  __shared__ int   minpos[QN];
  __shared__ float fst[4];
  __shared__ int   ist[4];
  const int tid  = threadIdx.x;
  const int lane = tid & 63;
  const int wave = tid >> 6;

  for (int i = tid; i < QN; i += 256) {
    m0[i] = B[i];
    m1[i] = B[QN + i];
    minpos[i] = 0x7fffffff;
  }
  for (int i = tid; i < NN; i += 256) {
    asg[i] = -1;
    unsigned long long key = 0ull;
    if (i >= 2) {
      unsigned vb = __float_as_uint(ad_g[i]);      // ad >= 0: bits monotone
      unsigned lo = ((unsigned)(1023 - i) << 16) | (unsigned)am_g[i];
      key = ((unsigned long long)vb << 32) | (unsigned long long)lo;
    }
    skey[i] = key;
  }
  for (int i = NN + tid; i < 1024; i += 256) skey[i] = 0ull;
  __syncthreads();

  // bitonic sort (descending), 512 pairs, 2 per thread, 4 waves
  for (int kk2 = 2; kk2 <= 1024; kk2 <<= 1) {
    for (int j = kk2 >> 1; j > 0; j >>= 1) {
#pragma unroll
      for (int k = 0; k < 2; ++k) {
        int g = tid + 256 * k;
        int t = ((g & ~(j - 1)) << 1) | (g & (j - 1));
        int l = t | j;
        unsigned long long a = skey[t], b = skey[l];
        bool sw = ((t & kk2) == 0) ? (a < b) : (a > b);
        if (sw) { skey[t] = b; skey[l] = a; }
      }
      __syncthreads();
    }
  }

  // payload gather (clamped pristine mirrors) + first-touch marking
#pragma unroll
  for (int k = 0; k < 4; ++k) {
    int pp = tid + 256 * k;
    unsigned long long key = skey[pp];
    int r = (int)(key & 0x1FF);
    spay[pp] = (unsigned long long)__float_as_uint(fminf(m0[r], 100.0f)) |
               ((unsigned long long)__float_as_uint(fminf(m1[r], 100.0f)) << 32);
    if (key != 0ull) atomicMin(&minpos[r], pp);
  }
  __syncthreads();
#pragma unroll
  for (int k = 0; k < 4; ++k) {
    int pp = tid + 256 * k;
    unsigned long long key = skey[pp];
    int r = (int)(key & 0x1FF);
    if (key != 0ull && minpos[r] == pp) skey[pp] |= 0x8000ull;
  }
  // initial top-2 multiset stats: wave 0 -> col 0, wave 1 -> col 1
  if (wave == 0) {
    float A1, A2; int C1, C2;
    wave_maxcount(m0, lane, INFINITY, A1, C1);
    wave_maxcount(m0, lane, A1, A2, C2);
    if (lane == 0) { fst[0] = A1; fst[1] = A2; ist[0] = C1; ist[1] = C2; }
  } else if (wave == 1) {
    float B1, B2; int D1, D2;
    wave_maxcount(m1, lane, INFINITY, B1, D1);
    wave_maxcount(m1, lane, B1, B2, D2);
    if (lane == 0) { fst[2] = B1; fst[3] = B2; ist[2] = D1; ist[3] = D2; }
  }
  __syncthreads();
  if (wave != 0) return;          // no barriers past this point

  float a1 = fst[0], a2 = fst[1], b1 = fst[2], b2 = fst[3];
  int   c1 = ist[0], c2 = ist[1], d1 = ist[2], d2 = ist[3];

  int p = 0, it = 0, w0 = -64;
  float cv = 0.0f, ix0 = 0.0f, ix1 = 0.0f;
  unsigned lo = 0; int row = 0; bool ft = false;
  int negpos0 = -1, negpos1 = -1, dt_m0 = -1, dt_m1 = -1;
  bool trivial0 = false, trivial1 = false;
  int asg0 = -1, asg1 = -1;

  while (it < NN) {
    if (p >= w0 + 64) {                      // reload 64-key window
      w0 = p & ~63;
      unsigned long long kk = skey[w0 + lane];
      unsigned long long yy = spay[w0 + lane];
      cv  = __uint_as_float((unsigned)(kk >> 32));
      lo  = (unsigned)kk;
      row = (int)(lo & 0x1FF);
      ft  = (lo & 0x8000u) != 0;
      ix0 = __uint_as_float((unsigned)yy);
      ix1 = __uint_as_float((unsigned)(yy >> 32));
    }
    float gap0 = (c1 >= 2) ? 0.0f : (a1 - a2);
    float gap1 = (d1 >= 2) ? 0.0f : (b1 - b2);
    float best = fmaxf(gap0, gap1);

    float x0 = trivial0 ? ((row == negpos0) ? -1e-07f : 0.0f)
                        : ((ft && row != dt_m0) ? ix0 : 0.0f);
    float x1 = trivial1 ? ((row == negpos1) ? -1e-07f : 0.0f)
                        : ((ft && row != dt_m1) ? ix1 : 0.0f);
    bool slow = ((!trivial0) && !(a1 > 0.0f && a2 > 0.0f)) ||
                ((!trivial1) && !(b1 > 0.0f && b2 > 0.0f));
    bool ev = slow ||
              (trivial0 ? (x0 != 0.0f) : (x0 == a1 || x0 == a2)) ||
              (trivial1 ? (x1 != 0.0f) : (x1 == b1 || x1 == b2));
    bool sel = !(cv > best);

    int base = p - w0;                       // 0..63
    unsigned long long valid = ~0ull << base;
    unsigned long long selm = __ballot(sel) & valid;
    unsigned long long evm  = __ballot(ev)  & valid;
    int lsel = selm ? (int)__builtin_ctzll(selm) : 64;
    int lev  = evm  ? (int)__builtin_ctzll(evm)  : 64;
    int lmin = (lsel < lev) ? lsel : lev;
    int pref = lmin - base;
    int rem = NN - it;
    if (pref > rem) pref = rem;

    if ((int)lane >= base && (int)lane < base + pref) {   // bulk clean pops
      m0[row] = 0.0f;
      m1[row] = 0.0f;
      asg[1023 - (int)(lo >> 16)] = row;
    }
    p += pref; it += pref;
    if (it >= NN) break;
    if (lmin == 64) continue;                // window exhausted -> reload

    WFENCE();                                // prefix writes visible to reads
    if (lsel <= lev) {
      // ---- selection event: col 0 or col 1 pick (it+1, p unchanged) ----
      int col = (gap1 > gap0) ? 1 : 0;
      if (col == 0) {
        int rw = trivial0 ? ((negpos0 == 0) ? 1 : 0) : wave_argmax(m0, lane);
        float x1p = m1[rw];
#pragma unroll
        for (int k = 0; k < QN / 64; ++k) m0[lane + 64 * k] = 0.0f;
        if (lane == 0) { m0[rw] = -1e-07f; m1[rw] = 0.0f; }
        WFENCE();
        a1 = 0.0f; c1 = QN - 1; a2 = -1e-07f; c2 = 1;
        trivial0 = true; negpos0 = rw;
        dt_m1 = rw;
        if (negpos1 == rw) negpos1 = -1;
        if (ms_update(x1p, b1, d1, b2, d2)) {
          WFENCE();
          wave_maxcount(m1, lane, INFINITY, b1, d1);
          wave_maxcount(m1, lane, b1, b2, d2);
        }
        asg0 = rw;
        if (asg1 == rw) asg1 = -1;
      } else {
        int rw = trivial1 ? ((negpos1 == 0) ? 1 : 0) : wave_argmax(m1, lane);
        float x0p = m0[rw];
#pragma unroll
        for (int k = 0; k < QN / 64; ++k) m1[lane + 64 * k] = 0.0f;
        if (lane == 0) { m1[rw] = -1e-07f; m0[rw] = 0.0f; }
        WFENCE();
        b1 = 0.0f; d1 = QN - 1; b2 = -1e-07f; d2 = 1;
        trivial1 = true; negpos1 = rw;
        dt_m0 = rw;
        if (negpos0 == rw) negpos0 = -1;
        if (ms_update(x0p, a1, c1, a2, c2)) {
          WFENCE();
          wave_maxcount(m0, lane, INFINITY, a1, c1);
          wave_maxcount(m0, lane, a1, a2, c2);
        }
        asg1 = rw;
        if (asg0 == rw) asg0 = -1;
      }
      ++it;
    } else {
      // ---- multiset event: one scalar pop at lane lmin (it+1, p+1) ----
      float cx0 = __shfl(x0, lmin);
      float cx1 = __shfl(x1, lmin);
      int crow  = __shfl(row, lmin);
      int ccol  = 1023 - __shfl((int)(lo >> 16), lmin);
      if (lane == 0) { m0[crow] = 0.0f; m1[crow] = 0.0f; asg[ccol] = crow; }
      if (negpos0 == crow) negpos0 = -1;
      if (negpos1 == crow) negpos1 = -1;
      if (ms_update(cx0, a1, c1, a2, c2)) {
        WFENCE();
        wave_maxcount(m0, lane, INFINITY, a1, c1);
        wave_maxcount(m0, lane, a1, a2, c2);
      }
      if (ms_update(cx1, b1, d1, b2, d2)) {
        WFENCE();
        wave_maxcount(m1, lane, INFINITY, b1, d1);
        wave_maxcount(m1, lane, b1, b2, d2);
      }
      if (asg0 == crow) asg0 = -1;
      if (asg1 == crow) asg1 = -1;
      ++p; ++it;
    }
  }

  if (lane == 0) { asg[0] = asg0; asg[1] = asg1; }
  WFENCE();
#pragma unroll
  for (int k = 0; k < NN / 64; ++k) {
    int i = lane + 64 * k;
    asg_out[i] = asg[i];
  }
}

// ---------- Stage 5: emit boolean as INT32 0/1, row-major [Q][N] ----------

__global__ void k_out(const int* __restrict__ asg, int* __restrict__ out, int total) {
  int t = blockIdx.x * blockDim.x + threadIdx.x;
  if (t >= total) return;
  int q = t / NN;
  int n = t - q * NN;
  out[t] = (asg[n] == q) ? 1 : 0;
}

extern "C" void kernel_launch(void* const* d_in, const int* in_sizes, int n_in,
                              void* d_out, int out_size, void* d_ws, size_t ws_size,
                              hipStream_t stream) {
  const float* logits  = (const float*)d_in[0];  // [32,512,92]
  const float* pboxes  = (const float*)d_in[1];  // [32,512,4]
  const float* tboxes  = (const float*)d_in[2];  // [768,4]
  const int*   tlabels = (const int*)d_in[3];    // [768]

  float* B    = (float*)d_ws;            // 393216 f32, column-major [N][Q]
  float* mx   = B + QN * NN;             // 16384
  float* sm   = mx + BSZ * QN;           // 16384
  float* ad   = sm + BSZ * QN;           // 768
  int*   am   = (int*)(ad + NN);         // 768
  int*   asgg = am + NN;                 // 768
  int*   out  = (int*)d_out;

  hipLaunchKernelGGL(k_softmax_stats, dim3((BSZ * QN) / SROWS), dim3(256), 0, stream,
                     logits, mx, sm);
  hipLaunchKernelGGL(k_build, dim3((QN * NN) / 256), dim3(256), 0, stream,
                     logits, pboxes, tboxes, tlabels, mx, sm, B);
  hipLaunchKernelGGL(k_init, dim3(NN / 4), dim3(256), 0, stream, B, ad, am);
  hipLaunchKernelGGL(k_scan, dim3(1), dim3(256), 0, stream, B, ad, am, asgg);
  hipLaunchKernelGGL(k_out, dim3((QN * NN) / 256), dim3(256), 0, stream,
                     asgg, out, QN * NN);
}